// Round 1
// baseline (6055.034 us; speedup 1.0000x reference)
//
#include <hip/hip_runtime.h>
#include <hip/hip_bf16.h>
#include <math.h>

#define Bsz 2
#define Sq  2048
#define Dm  2048
#define Hn  16
#define KVn 4
#define HDn 128

#define TILE_M 64
#define TILE_N 64
#define TILE_K 16

// C = A(MxK) * B(KxN). SPLIT: write C as (B, NH, S, HD) head-split layout,
// else plain row-major (MxN).
template <bool SPLIT>
__global__ __launch_bounds__(256) void gemm_kernel(
    const float* __restrict__ A, const float* __restrict__ Bm,
    float* __restrict__ C, int M, int N, int K, int NH)
{
    __shared__ __align__(16) float As[TILE_K][TILE_M]; // [k][m]
    __shared__ __align__(16) float Bs[TILE_K][TILE_N]; // [k][n]

    const int tid  = threadIdx.y * 16 + threadIdx.x;   // 0..255
    const int row0 = blockIdx.y * TILE_M;
    const int col0 = blockIdx.x * TILE_N;

    // A-tile load mapping: thread -> (m, 4 consecutive k) as one float4
    const int mA = tid >> 2;          // 0..63
    const int kA = (tid & 3) * 4;     // 0,4,8,12
    // B-tile load mapping: thread -> (k, 4 consecutive n) as one float4
    const int kB = tid >> 4;          // 0..15
    const int nB = (tid & 15) * 4;    // 0..60

    float acc[4][4] = {};

    for (int k0 = 0; k0 < K; k0 += TILE_K) {
        float4 a4 = *(const float4*)(A + (size_t)(row0 + mA) * K + k0 + kA);
        float4 b4 = *(const float4*)(Bm + (size_t)(k0 + kB) * N + col0 + nB);
        As[kA + 0][mA] = a4.x;
        As[kA + 1][mA] = a4.y;
        As[kA + 2][mA] = a4.z;
        As[kA + 3][mA] = a4.w;
        *(float4*)&Bs[kB][nB] = b4;
        __syncthreads();

#pragma unroll
        for (int kk = 0; kk < TILE_K; ++kk) {
            float4 av = *(const float4*)&As[kk][threadIdx.y * 4];
            float4 bv = *(const float4*)&Bs[kk][threadIdx.x * 4];
            float a[4] = {av.x, av.y, av.z, av.w};
            float b[4] = {bv.x, bv.y, bv.z, bv.w};
#pragma unroll
            for (int i = 0; i < 4; ++i)
#pragma unroll
                for (int j = 0; j < 4; ++j)
                    acc[i][j] = fmaf(a[i], b[j], acc[i][j]);
        }
        __syncthreads();
    }

#pragma unroll
    for (int i = 0; i < 4; ++i) {
        const int m = row0 + threadIdx.y * 4 + i;
#pragma unroll
        for (int j = 0; j < 4; ++j) {
            const int n = col0 + threadIdx.x * 4 + j;
            if (SPLIT) {
                const int b  = m / Sq;
                const int s  = m % Sq;
                const int h  = n / HDn;
                const int d2 = n % HDn;
                C[(((size_t)b * NH + h) * Sq + s) * HDn + d2] = acc[i][j];
            } else {
                C[(size_t)m * N + n] = acc[i][j];
            }
        }
    }
}

// In-place LLaMA RoPE on X laid out (B, NHx, S, HD). One thread per (i,i+64) pair.
__global__ __launch_bounds__(256) void rope_kernel(
    float* __restrict__ X, const int* __restrict__ pos_ids, int NHx, int total)
{
    int idx = blockIdx.x * blockDim.x + threadIdx.x;
    if (idx >= total) return;
    const int i = idx & 63;
    int rest = idx >> 6;
    const int s = rest % Sq; rest /= Sq;
    const int h = rest % NHx;
    const int b = rest / NHx;

    const int pos = pos_ids[b * Sq + s];
    const float e   = -(float)(2 * i) * (1.0f / (float)HDn);
    const float inv = powf(500000.0f, e);
    const float f   = (float)pos * inv;
    const float c   = cosf(f);
    const float sn  = sinf(f);

    float* p = X + (((size_t)b * NHx + h) * Sq + s) * HDn;
    const float x1 = p[i];
    const float x2 = p[i + 64];
    p[i]      = x1 * c - x2 * sn;
    p[i + 64] = x2 * c + x1 * sn;
}

// Flash attention, one wave per query row. Q:(B,H,S,HD) K/V:(B,KV,S,HD)
// Out: (B, S, H*HD)
__global__ __launch_bounds__(256) void attn_kernel(
    const float* __restrict__ Q, const float* __restrict__ Kt,
    const float* __restrict__ Vt, float* __restrict__ Out)
{
    const int gw   = blockIdx.x * 4 + (threadIdx.x >> 6); // global wave id
    const int lane = threadIdx.x & 63;

    const int s  = gw % Sq;
    const int bh = gw / Sq;
    const int h  = bh % Hn;
    const int b  = bh / Hn;
    const int kvh = h >> 2; // h / (H/KV)

    const float scale = 0.08838834764831845f; // 1/sqrt(128)

    const float* qp = Q + (((size_t)b * Hn + h) * Sq + s) * HDn;
    float2 q = *(const float2*)(qp + lane * 2);
    q.x *= scale; q.y *= scale;

    const float* kp = Kt + ((size_t)b * KVn + kvh) * Sq * HDn;
    const float* vp = Vt + ((size_t)b * KVn + kvh) * Sq * HDn;

    float m = -1e30f, l = 0.f, ax = 0.f, ay = 0.f;
    for (int t = 0; t <= s; ++t) {
        float2 kv = *(const float2*)(kp + (size_t)t * HDn + lane * 2);
        float d = q.x * kv.x + q.y * kv.y;
        d += __shfl_xor(d, 32);
        d += __shfl_xor(d, 16);
        d += __shfl_xor(d, 8);
        d += __shfl_xor(d, 4);
        d += __shfl_xor(d, 2);
        d += __shfl_xor(d, 1);

        const float nm = fmaxf(m, d);
        const float al = __expf(m - nm);
        const float p  = __expf(d - nm);
        float2 vv = *(const float2*)(vp + (size_t)t * HDn + lane * 2);
        ax = ax * al + p * vv.x;
        ay = ay * al + p * vv.y;
        l  = l * al + p;
        m  = nm;
    }
    const float invl = 1.0f / l;
    float* op = Out + ((size_t)b * Sq + s) * (Hn * HDn) + h * HDn + lane * 2;
    op[0] = ax * invl;
    op[1] = ay * invl;
}

extern "C" void kernel_launch(void* const* d_in, const int* in_sizes, int n_in,
                              void* d_out, int out_size, void* d_ws, size_t ws_size,
                              hipStream_t stream)
{
    const float* x   = (const float*)d_in[0];
    const float* wq  = (const float*)d_in[1];
    const float* wk  = (const float*)d_in[2];
    const float* wv  = (const float*)d_in[3];
    const float* wo  = (const float*)d_in[4];
    // d_in[5] = attn_mask (pure causal; handled structurally)
    const int* pos   = (const int*)d_in[6];
    float* out = (float*)d_out;

    float* ws = (float*)d_ws;
    float* Qw = ws;                                  // B*H*S*HD  = 8388608
    float* Kw = Qw + (size_t)Bsz * Hn * Sq * HDn;    // B*KV*S*HD = 2097152
    float* Vw = Kw + (size_t)Bsz * KVn * Sq * HDn;
    float* AO = Vw + (size_t)Bsz * KVn * Sq * HDn;   // B*S*H*HD  = 8388608

    const int M = Bsz * Sq; // 4096

    dim3 blk(16, 16);
    // Q = x @ wq  -> (B,H,S,HD)
    gemm_kernel<true><<<dim3((Hn * HDn) / TILE_N, M / TILE_M), blk, 0, stream>>>(
        x, wq, Qw, M, Hn * HDn, Dm, Hn);
    // K = x @ wk  -> (B,KV,S,HD)
    gemm_kernel<true><<<dim3((KVn * HDn) / TILE_N, M / TILE_M), blk, 0, stream>>>(
        x, wk, Kw, M, KVn * HDn, Dm, KVn);
    // V = x @ wv  -> (B,KV,S,HD)
    gemm_kernel<true><<<dim3((KVn * HDn) / TILE_N, M / TILE_M), blk, 0, stream>>>(
        x, wv, Vw, M, KVn * HDn, Dm, KVn);

    // RoPE in-place on Q and K
    {
        int totQ = Bsz * Hn * Sq * 64;
        rope_kernel<<<(totQ + 255) / 256, 256, 0, stream>>>(Qw, pos, Hn, totQ);
        int totK = Bsz * KVn * Sq * 64;
        rope_kernel<<<(totK + 255) / 256, 256, 0, stream>>>(Kw, pos, KVn, totK);
    }

    // Attention -> AO (B,S,H*HD)
    attn_kernel<<<(Bsz * Hn * Sq) / 4, 256, 0, stream>>>(Qw, Kw, Vw, AO);

    // out = AO @ wo
    gemm_kernel<false><<<dim3(Dm / TILE_N, M / TILE_M), blk, 0, stream>>>(
        AO, wo, out, M, Dm, Dm, 1);
}

// Round 2
// 1699.204 us; speedup vs baseline: 3.5635x; 3.5635x over previous
//
#include <hip/hip_runtime.h>
#include <hip/hip_bf16.h>
#include <math.h>

#define Bsz 2
#define Sq  2048
#define Dm  2048
#define Hn  16
#define KVn 4
#define HDn 128

#define TILE_M 64
#define TILE_N 64
#define TILE_K 16

typedef __attribute__((ext_vector_type(8))) short bf16x8;
typedef __attribute__((ext_vector_type(4))) float f32x4;

// ---------------- fp32 GEMM (projections + output proj) ----------------
// C = A(MxK) * B(KxN). SPLIT: write C as (B, NH, S, HD) head-split layout.
template <bool SPLIT>
__global__ __launch_bounds__(256) void gemm_kernel(
    const float* __restrict__ A, const float* __restrict__ Bm,
    float* __restrict__ C, int M, int N, int K, int NH)
{
    __shared__ __align__(16) float As[TILE_K][TILE_M];
    __shared__ __align__(16) float Bs[TILE_K][TILE_N];

    const int tid  = threadIdx.y * 16 + threadIdx.x;
    const int row0 = blockIdx.y * TILE_M;
    const int col0 = blockIdx.x * TILE_N;

    const int mA = tid >> 2;
    const int kA = (tid & 3) * 4;
    const int kB = tid >> 4;
    const int nB = (tid & 15) * 4;

    float acc[4][4] = {};

    for (int k0 = 0; k0 < K; k0 += TILE_K) {
        float4 a4 = *(const float4*)(A + (size_t)(row0 + mA) * K + k0 + kA);
        float4 b4 = *(const float4*)(Bm + (size_t)(k0 + kB) * N + col0 + nB);
        As[kA + 0][mA] = a4.x;
        As[kA + 1][mA] = a4.y;
        As[kA + 2][mA] = a4.z;
        As[kA + 3][mA] = a4.w;
        *(float4*)&Bs[kB][nB] = b4;
        __syncthreads();

#pragma unroll
        for (int kk = 0; kk < TILE_K; ++kk) {
            float4 av = *(const float4*)&As[kk][threadIdx.y * 4];
            float4 bv = *(const float4*)&Bs[kk][threadIdx.x * 4];
            float a[4] = {av.x, av.y, av.z, av.w};
            float b[4] = {bv.x, bv.y, bv.z, bv.w};
#pragma unroll
            for (int i = 0; i < 4; ++i)
#pragma unroll
                for (int j = 0; j < 4; ++j)
                    acc[i][j] = fmaf(a[i], b[j], acc[i][j]);
        }
        __syncthreads();
    }

#pragma unroll
    for (int i = 0; i < 4; ++i) {
        const int m = row0 + threadIdx.y * 4 + i;
#pragma unroll
        for (int j = 0; j < 4; ++j) {
            const int n = col0 + threadIdx.x * 4 + j;
            if (SPLIT) {
                const int b  = m / Sq;
                const int s  = m % Sq;
                const int h  = n / HDn;
                const int d2 = n % HDn;
                C[(((size_t)b * NH + h) * Sq + s) * HDn + d2] = acc[i][j];
            } else {
                C[(size_t)m * N + n] = acc[i][j];
            }
        }
    }
}

// ------------- RoPE fp32 -> bf16 (optionally folds softmax scale) -------------
// X: (B, NHx, S, HD) fp32 -> Y same layout bf16. One thread per (i, i+64) pair.
__global__ __launch_bounds__(256) void rope_conv_kernel(
    const float* __restrict__ X, __hip_bfloat16* __restrict__ Y,
    const int* __restrict__ pos_ids, int NHx, float scale, int total)
{
    int idx = blockIdx.x * blockDim.x + threadIdx.x;
    if (idx >= total) return;
    const int i = idx & 63;
    int rest = idx >> 6;
    const int s = rest % Sq; rest /= Sq;
    const int h = rest % NHx;
    const int b = rest / NHx;

    const int pos = pos_ids[b * Sq + s];
    const float e   = -(float)(2 * i) * (1.0f / (float)HDn);
    const float inv = powf(500000.0f, e);
    const float f   = (float)pos * inv;
    const float c   = cosf(f);
    const float sn  = sinf(f);

    const size_t base = (((size_t)b * NHx + h) * Sq + s) * HDn;
    const float x1 = X[base + i];
    const float x2 = X[base + i + 64];
    Y[base + i]      = __float2bfloat16((x1 * c - x2 * sn) * scale);
    Y[base + i + 64] = __float2bfloat16((x2 * c + x1 * sn) * scale);
}

// ------------- V fp32 (B,KV,S,HD) -> bf16 transposed (B,KV,HD,S) -------------
__global__ __launch_bounds__(256) void vconv_kernel(
    const float* __restrict__ V, __hip_bfloat16* __restrict__ Vt)
{
    __shared__ float t[32][33];
    const int bk = blockIdx.z;
    const int s0 = blockIdx.x * 32;
    const int d0 = blockIdx.y * 32;
    const int tx = threadIdx.x, ty = threadIdx.y;

    const float* vp = V + (size_t)bk * Sq * HDn;
#pragma unroll
    for (int r = 0; r < 4; ++r) {
        const int row = ty + 8 * r;
        t[row][tx] = vp[(size_t)(s0 + row) * HDn + d0 + tx];
    }
    __syncthreads();
    __hip_bfloat16* op = Vt + (size_t)bk * HDn * Sq;
#pragma unroll
    for (int r = 0; r < 4; ++r) {
        const int row = ty + 8 * r;
        op[(size_t)(d0 + row) * Sq + s0 + tx] = __float2bfloat16(t[tx][row]);
    }
}

// ------------- MFMA flash attention -------------
// Qb: (B,H,S,HD) bf16, pre-scaled by 1/sqrt(HD). Kb: (B,KV,S,HD) bf16.
// Vtb: (B,KV,HD,S) bf16. Out: (B,S,H*HD) fp32.
// One wave (64-thread block) per 16 query rows.
__global__ __launch_bounds__(64) void fattn_kernel(
    const __hip_bfloat16* __restrict__ Qb, const __hip_bfloat16* __restrict__ Kb,
    const __hip_bfloat16* __restrict__ Vtb, float* __restrict__ Out)
{
    __shared__ float P[16][68];   // pad: stride 68 words -> 2-way banks (free)

    const int lane = threadIdx.x & 63;
    const int m16  = lane & 15;
    const int g4   = lane >> 4;

    const int qtile = blockIdx.x & 127;
    const int bh    = blockIdx.x >> 7;
    const int h     = bh & 15;
    const int b     = bh >> 4;
    const int kv    = h >> 2;
    const int q0    = qtile << 4;

    // Q fragments (A-operand): A[m=lane&15][k=g4*8+j], 4 chunks over HD=128
    const __hip_bfloat16* qp =
        Qb + (((size_t)b * Hn + h) * Sq + q0 + m16) * HDn + g4 * 8;
    bf16x8 qf[4];
#pragma unroll
    for (int c = 0; c < 4; ++c) qf[c] = *(const bf16x8*)(qp + c * 32);

    const __hip_bfloat16* kbase = Kb  + ((size_t)b * KVn + kv) * Sq * HDn;
    const __hip_bfloat16* vbase = Vtb + ((size_t)b * KVn + kv) * (size_t)HDn * Sq;

    f32x4 O[8];
#pragma unroll
    for (int t = 0; t < 8; ++t) O[t] = (f32x4){0.f, 0.f, 0.f, 0.f};
    float mrow[4] = {-1e30f, -1e30f, -1e30f, -1e30f};
    float lrow[4] = {0.f, 0.f, 0.f, 0.f};

    const int nfull = q0 >> 6;   // chunk index of the boundary (masked) chunk

    for (int ch = 0; ch <= nfull; ++ch) {
        const int kt = ch << 6;

        // ---- scores: 4 key-subtiles of 16 keys ----
        f32x4 sc[4];
#pragma unroll
        for (int f = 0; f < 4; ++f) {
            f32x4 acc = (f32x4){0.f, 0.f, 0.f, 0.f};
            const __hip_bfloat16* kp =
                kbase + (size_t)(kt + f * 16 + m16) * HDn + g4 * 8;
#pragma unroll
            for (int c = 0; c < 4; ++c) {
                bf16x8 kf = *(const bf16x8*)(kp + c * 32);
                acc = __builtin_amdgcn_mfma_f32_16x16x32_bf16(qf[c], kf, acc, 0, 0, 0);
            }
            sc[f] = acc;
        }

        if (ch == nfull) {  // causal mask within boundary chunk
#pragma unroll
            for (int f = 0; f < 4; ++f)
#pragma unroll
                for (int i = 0; i < 4; ++i) {
                    const int kg = kt + f * 16 + m16;
                    const int qg = q0 + g4 * 4 + i;
                    if (kg > qg) sc[f][i] = -1e30f;
                }
        }

        // ---- online softmax over the 64 new cols, per row i ----
        float alpha[4];
#pragma unroll
        for (int i = 0; i < 4; ++i) {
            float mx = fmaxf(fmaxf(sc[0][i], sc[1][i]), fmaxf(sc[2][i], sc[3][i]));
            mx = fmaxf(mx, __shfl_xor(mx, 1));
            mx = fmaxf(mx, __shfl_xor(mx, 2));
            mx = fmaxf(mx, __shfl_xor(mx, 4));
            mx = fmaxf(mx, __shfl_xor(mx, 8));
            const float nm = fmaxf(mrow[i], mx);
            alpha[i] = __expf(mrow[i] - nm);
            mrow[i]  = nm;
            float ps = 0.f;
#pragma unroll
            for (int f = 0; f < 4; ++f) {
                sc[f][i] = __expf(sc[f][i] - nm);
                ps += sc[f][i];
            }
            ps += __shfl_xor(ps, 1);
            ps += __shfl_xor(ps, 2);
            ps += __shfl_xor(ps, 4);
            ps += __shfl_xor(ps, 8);
            lrow[i] = lrow[i] * alpha[i] + ps;
        }

        // rescale O
#pragma unroll
        for (int t = 0; t < 8; ++t)
#pragma unroll
            for (int i = 0; i < 4; ++i) O[t][i] *= alpha[i];

        // ---- P: C-layout -> LDS -> A-layout ----
#pragma unroll
        for (int f = 0; f < 4; ++f)
#pragma unroll
            for (int i = 0; i < 4; ++i)
                P[g4 * 4 + i][f * 16 + m16] = sc[f][i];

        float4 pa0 = *(float4*)&P[m16][g4 * 8];
        float4 pa1 = *(float4*)&P[m16][g4 * 8 + 4];
        float4 pb0 = *(float4*)&P[m16][32 + g4 * 8];
        float4 pb1 = *(float4*)&P[m16][32 + g4 * 8 + 4];

        bf16x8 a0, a1;
        {
            float pv0[8] = {pa0.x, pa0.y, pa0.z, pa0.w, pa1.x, pa1.y, pa1.z, pa1.w};
            float pv1[8] = {pb0.x, pb0.y, pb0.z, pb0.w, pb1.x, pb1.y, pb1.z, pb1.w};
#pragma unroll
            for (int j = 0; j < 8; ++j) {
                __hip_bfloat16 h0 = __float2bfloat16(pv0[j]);
                __hip_bfloat16 h1 = __float2bfloat16(pv1[j]);
                a0[j] = *reinterpret_cast<short*>(&h0);
                a1[j] = *reinterpret_cast<short*>(&h1);
            }
        }

        // ---- PV: O[q][d] += P[q][k] * V[k][d], B-frag from V^T ----
#pragma unroll
        for (int t = 0; t < 8; ++t) {
            const __hip_bfloat16* vp =
                vbase + (size_t)(t * 16 + m16) * Sq + kt + g4 * 8;
            bf16x8 v0 = *(const bf16x8*)(vp);
            bf16x8 v1 = *(const bf16x8*)(vp + 32);
            O[t] = __builtin_amdgcn_mfma_f32_16x16x32_bf16(a0, v0, O[t], 0, 0, 0);
            O[t] = __builtin_amdgcn_mfma_f32_16x16x32_bf16(a1, v1, O[t], 0, 0, 0);
        }
    }

    // ---- epilogue: O /= l, write (B,S,H*HD) ----
    float inv[4];
#pragma unroll
    for (int i = 0; i < 4; ++i) inv[i] = 1.0f / lrow[i];

    float* op = Out + ((size_t)b * Sq + q0) * (Hn * HDn) + h * HDn;
#pragma unroll
    for (int t = 0; t < 8; ++t)
#pragma unroll
        for (int i = 0; i < 4; ++i)
            op[(size_t)(g4 * 4 + i) * (Hn * HDn) + t * 16 + m16] = O[t][i] * inv[i];
}

extern "C" void kernel_launch(void* const* d_in, const int* in_sizes, int n_in,
                              void* d_out, int out_size, void* d_ws, size_t ws_size,
                              hipStream_t stream)
{
    const float* x   = (const float*)d_in[0];
    const float* wq  = (const float*)d_in[1];
    const float* wk  = (const float*)d_in[2];
    const float* wv  = (const float*)d_in[3];
    const float* wo  = (const float*)d_in[4];
    const int* pos   = (const int*)d_in[6];
    float* out = (float*)d_out;

    const size_t nQ  = (size_t)Bsz * Hn * Sq * HDn;   // 8388608
    const size_t nKV = (size_t)Bsz * KVn * Sq * HDn;  // 2097152

    float* ws = (float*)d_ws;
    float* Qw = ws;
    float* Kw = Qw + nQ;
    float* Vw = Kw + nKV;
    float* AO = Vw + nKV;
    __hip_bfloat16* Qb  = (__hip_bfloat16*)(AO + nQ);
    __hip_bfloat16* Kb  = Qb + nQ;
    __hip_bfloat16* Vtb = Kb + nKV;

    const int M = Bsz * Sq; // 4096

    dim3 blk(16, 16);
    gemm_kernel<true><<<dim3((Hn * HDn) / TILE_N, M / TILE_M), blk, 0, stream>>>(
        x, wq, Qw, M, Hn * HDn, Dm, Hn);
    gemm_kernel<true><<<dim3((KVn * HDn) / TILE_N, M / TILE_M), blk, 0, stream>>>(
        x, wk, Kw, M, KVn * HDn, Dm, KVn);
    gemm_kernel<true><<<dim3((KVn * HDn) / TILE_N, M / TILE_M), blk, 0, stream>>>(
        x, wv, Vw, M, KVn * HDn, Dm, KVn);

    {
        const float qscale = 0.08838834764831845f; // 1/sqrt(128)
        int totQ = Bsz * Hn * Sq * 64;
        rope_conv_kernel<<<(totQ + 255) / 256, 256, 0, stream>>>(
            Qw, Qb, pos, Hn, qscale, totQ);
        int totK = Bsz * KVn * Sq * 64;
        rope_conv_kernel<<<(totK + 255) / 256, 256, 0, stream>>>(
            Kw, Kb, pos, KVn, 1.0f, totK);
    }

    vconv_kernel<<<dim3(Sq / 32, HDn / 32, Bsz * KVn), dim3(32, 8), 0, stream>>>(
        Vw, Vtb);

    fattn_kernel<<<Bsz * Hn * (Sq / 16), 64, 0, stream>>>(Qb, Kb, Vtb, AO);

    gemm_kernel<false><<<dim3(Dm / TILE_N, M / TILE_M), blk, 0, stream>>>(
        AO, wo, out, M, Dm, Dm, 1);
}

// Round 3
// 636.605 us; speedup vs baseline: 9.5115x; 2.6692x over previous
//
#include <hip/hip_runtime.h>
#include <hip/hip_bf16.h>
#include <math.h>

#define Bsz 2
#define Sq  2048
#define Dm  2048
#define Hn  16
#define KVn 4
#define HDn 128

typedef __attribute__((ext_vector_type(8))) short bf16x8;
typedef __attribute__((ext_vector_type(4))) float f32x4;

__device__ __forceinline__ short f2b(float f) {
    __hip_bfloat16 h = __float2bfloat16(f);
    return *reinterpret_cast<short*>(&h);
}

// ---------------- fp32 -> bf16 elementwise (x) ----------------
__global__ __launch_bounds__(256) void f2b_kernel(
    const float* __restrict__ X, short* __restrict__ Y, int n4)
{
    int i = blockIdx.x * 256 + threadIdx.x;
    if (i >= n4) return;
    float4 v = ((const float4*)X)[i];
    short4 o;
    o.x = f2b(v.x); o.y = f2b(v.y); o.z = f2b(v.z); o.w = f2b(v.w);
    ((short4*)Y)[i] = o;
}

// ------------- W (KxN fp32) -> Wt (NxK bf16), rows offset into fused buffer -------------
__global__ __launch_bounds__(256) void wconvT_kernel(
    const float* __restrict__ W, short* __restrict__ Wt, int N, int rowOff)
{
    __shared__ float t[32][33];
    const int k0 = blockIdx.y * 32;
    const int n0 = blockIdx.x * 32;
    const int tx = threadIdx.x, ty = threadIdx.y;
#pragma unroll
    for (int r = 0; r < 4; ++r) {
        const int row = ty + 8 * r;
        t[row][tx] = W[(size_t)(k0 + row) * N + n0 + tx];
    }
    __syncthreads();
#pragma unroll
    for (int r = 0; r < 4; ++r) {
        const int row = ty + 8 * r;
        Wt[(size_t)(rowOff + n0 + row) * Dm + k0 + tx] = f2b(t[tx][row]);
    }
}

// ---------------- bf16 MFMA GEMM: C(MxN fp32) = A(MxK) * Bt(NxK)^T ----------------
// 128x128 tile, BK=64, 4 waves of 64x64, global_load_lds staging, XOR-swizzled LDS.
__global__ __launch_bounds__(256) void gemm_bt_kernel(
    const short* __restrict__ A, const short* __restrict__ Bt,
    float* __restrict__ C, int M, int N, int K)
{
    __shared__ __align__(16) short As[128 * 64];
    __shared__ __align__(16) short Bs[128 * 64];

    const int tid  = threadIdx.x;
    const int w    = tid >> 6;
    const int lane = tid & 63;
    const int m16  = lane & 15;
    const int g4   = lane >> 4;
    const int wm   = w >> 1, wn = w & 1;

    const int row0 = blockIdx.y * 128;
    const int col0 = blockIdx.x * 128;

    const short* Ab = A  + (size_t)row0 * K;
    const short* Bb = Bt + (size_t)col0 * K;

    // staging: chunk g = r*256 + tid; row = r*32 + (tid>>3); oct = tid&7
    const int trow = tid >> 3;
    const int soct = (tid & 7) ^ (trow & 7);   // XOR swizzle (r*32 preserves row&7)

    f32x4 acc[4][4];
#pragma unroll
    for (int i = 0; i < 4; ++i)
#pragma unroll
        for (int j = 0; j < 4; ++j) acc[i][j] = (f32x4){0.f, 0.f, 0.f, 0.f};

    for (int k0 = 0; k0 < K; k0 += 64) {
#pragma unroll
        for (int r = 0; r < 4; ++r) {
            const short* gp = Ab + (size_t)(r * 32 + trow) * K + k0 + soct * 8;
            short* lp = &As[(size_t)(r * 256 + w * 64) * 8];
            __builtin_amdgcn_global_load_lds(
                (const __attribute__((address_space(1))) void*)gp,
                (__attribute__((address_space(3))) void*)lp, 16, 0, 0);
        }
#pragma unroll
        for (int r = 0; r < 4; ++r) {
            const short* gp = Bb + (size_t)(r * 32 + trow) * K + k0 + soct * 8;
            short* lp = &Bs[(size_t)(r * 256 + w * 64) * 8];
            __builtin_amdgcn_global_load_lds(
                (const __attribute__((address_space(1))) void*)gp,
                (__attribute__((address_space(3))) void*)lp, 16, 0, 0);
        }
        __syncthreads();

#pragma unroll
        for (int kc = 0; kc < 2; ++kc) {
            bf16x8 a[4], b[4];
            const int swz = (kc * 4 + g4) ^ (m16 & 7);
#pragma unroll
            for (int s = 0; s < 4; ++s) {
                const int rowA = wm * 64 + s * 16 + m16;
                a[s] = *(const bf16x8*)&As[rowA * 64 + swz * 8];
                const int rowB = wn * 64 + s * 16 + m16;
                b[s] = *(const bf16x8*)&Bs[rowB * 64 + swz * 8];
            }
#pragma unroll
            for (int i = 0; i < 4; ++i)
#pragma unroll
                for (int j = 0; j < 4; ++j)
                    acc[i][j] = __builtin_amdgcn_mfma_f32_16x16x32_bf16(
                        a[i], b[j], acc[i][j], 0, 0, 0);
        }
        __syncthreads();
    }

#pragma unroll
    for (int i = 0; i < 4; ++i) {
        const int mbase = row0 + wm * 64 + i * 16 + g4 * 4;
#pragma unroll
        for (int j = 0; j < 4; ++j) {
            const int n = col0 + wn * 64 + j * 16 + m16;
#pragma unroll
            for (int r = 0; r < 4; ++r)
                C[(size_t)(mbase + r) * N + n] = acc[i][j][r];
        }
    }
}

// ------------- RoPE from C3 (B,S,3072) fp32 -> bf16 split layout -------------
__global__ __launch_bounds__(256) void rope_conv_kernel(
    const float* __restrict__ C3, short* __restrict__ Y,
    const int* __restrict__ pos_ids, int NHx, int colOff, float scale, int total)
{
    int idx = blockIdx.x * blockDim.x + threadIdx.x;
    if (idx >= total) return;
    const int i = idx & 63;
    int rest = idx >> 6;
    const int s = rest % Sq; rest /= Sq;
    const int h = rest % NHx;
    const int b = rest / NHx;

    const int pos = pos_ids[b * Sq + s];
    const float e   = -(float)(2 * i) * (1.0f / (float)HDn);
    const float inv = powf(500000.0f, e);
    const float f   = (float)pos * inv;
    const float c   = cosf(f);
    const float sn  = sinf(f);

    const float* src = C3 + ((size_t)(b * Sq + s)) * 3072 + colOff + h * HDn;
    const float x1 = src[i];
    const float x2 = src[i + 64];
    const size_t dst = (((size_t)b * NHx + h) * Sq + s) * HDn;
    Y[dst + i]      = f2b((x1 * c - x2 * sn) * scale);
    Y[dst + i + 64] = f2b((x2 * c + x1 * sn) * scale);
}

// ------------- V region of C3 -> bf16 transposed (B,KV,HD,S) -------------
__global__ __launch_bounds__(256) void vconv_kernel(
    const float* __restrict__ C3, short* __restrict__ Vt)
{
    __shared__ float t[32][33];
    const int bk = blockIdx.z;
    const int b  = bk >> 2, kv = bk & 3;
    const int s0 = blockIdx.x * 32;
    const int d0 = blockIdx.y * 32;
    const int tx = threadIdx.x, ty = threadIdx.y;

#pragma unroll
    for (int r = 0; r < 4; ++r) {
        const int row = ty + 8 * r;  // s-local
        t[row][tx] = C3[((size_t)(b * Sq + s0 + row)) * 3072 + 2560 + kv * HDn + d0 + tx];
    }
    __syncthreads();
#pragma unroll
    for (int r = 0; r < 4; ++r) {
        const int row = ty + 8 * r;  // d-local
        Vt[((size_t)bk * HDn + d0 + row) * Sq + s0 + tx] = f2b(t[tx][row]);
    }
}

// ------------- MFMA flash attention, one wave per 16 query rows -------------
// Qb: (B,H,S,HD) bf16 pre-scaled. Kb: (B,KV,S,HD) bf16. Vtb: (B,KV,HD,S) bf16.
// AOb: (B,S,H*HD) bf16.
__global__ __launch_bounds__(64) void fattn_kernel(
    const short* __restrict__ Qb, const short* __restrict__ Kb,
    const short* __restrict__ Vtb, short* __restrict__ AOb)
{
    __shared__ float P[16][68];

    const int lane = threadIdx.x & 63;
    const int m16  = lane & 15;
    const int g4   = lane >> 4;

    const int qtile = blockIdx.x & 127;
    const int bh    = blockIdx.x >> 7;
    const int h     = bh & 15;
    const int b     = bh >> 4;
    const int kv    = h >> 2;
    const int q0    = qtile << 4;

    const short* qp = Qb + (((size_t)b * Hn + h) * Sq + q0 + m16) * HDn + g4 * 8;
    bf16x8 qf[4];
#pragma unroll
    for (int c = 0; c < 4; ++c) qf[c] = *(const bf16x8*)(qp + c * 32);

    const short* kbase = Kb  + ((size_t)b * KVn + kv) * Sq * HDn;
    const short* vbase = Vtb + ((size_t)b * KVn + kv) * (size_t)HDn * Sq;

    f32x4 O[8];
#pragma unroll
    for (int t = 0; t < 8; ++t) O[t] = (f32x4){0.f, 0.f, 0.f, 0.f};
    float mrow[4] = {-1e30f, -1e30f, -1e30f, -1e30f};
    float lrow[4] = {0.f, 0.f, 0.f, 0.f};

    const int nfull = q0 >> 6;

    for (int ch = 0; ch <= nfull; ++ch) {
        const int kt = ch << 6;

        f32x4 sc[4];
#pragma unroll
        for (int f = 0; f < 4; ++f) {
            f32x4 acc = (f32x4){0.f, 0.f, 0.f, 0.f};
            const short* kp = kbase + (size_t)(kt + f * 16 + m16) * HDn + g4 * 8;
#pragma unroll
            for (int c = 0; c < 4; ++c) {
                bf16x8 kf = *(const bf16x8*)(kp + c * 32);
                acc = __builtin_amdgcn_mfma_f32_16x16x32_bf16(qf[c], kf, acc, 0, 0, 0);
            }
            sc[f] = acc;
        }

        if (ch == nfull) {
#pragma unroll
            for (int f = 0; f < 4; ++f)
#pragma unroll
                for (int i = 0; i < 4; ++i) {
                    const int kg = kt + f * 16 + m16;
                    const int qg = q0 + g4 * 4 + i;
                    if (kg > qg) sc[f][i] = -1e30f;
                }
        }

        float alpha[4];
#pragma unroll
        for (int i = 0; i < 4; ++i) {
            float mx = fmaxf(fmaxf(sc[0][i], sc[1][i]), fmaxf(sc[2][i], sc[3][i]));
            mx = fmaxf(mx, __shfl_xor(mx, 1));
            mx = fmaxf(mx, __shfl_xor(mx, 2));
            mx = fmaxf(mx, __shfl_xor(mx, 4));
            mx = fmaxf(mx, __shfl_xor(mx, 8));
            const float nm = fmaxf(mrow[i], mx);
            alpha[i] = __expf(mrow[i] - nm);
            mrow[i]  = nm;
            float ps = 0.f;
#pragma unroll
            for (int f = 0; f < 4; ++f) {
                sc[f][i] = __expf(sc[f][i] - nm);
                ps += sc[f][i];
            }
            ps += __shfl_xor(ps, 1);
            ps += __shfl_xor(ps, 2);
            ps += __shfl_xor(ps, 4);
            ps += __shfl_xor(ps, 8);
            lrow[i] = lrow[i] * alpha[i] + ps;
        }

#pragma unroll
        for (int t = 0; t < 8; ++t)
#pragma unroll
            for (int i = 0; i < 4; ++i) O[t][i] *= alpha[i];

#pragma unroll
        for (int f = 0; f < 4; ++f)
#pragma unroll
            for (int i = 0; i < 4; ++i)
                P[g4 * 4 + i][f * 16 + m16] = sc[f][i];

        float4 pa0 = *(float4*)&P[m16][g4 * 8];
        float4 pa1 = *(float4*)&P[m16][g4 * 8 + 4];
        float4 pb0 = *(float4*)&P[m16][32 + g4 * 8];
        float4 pb1 = *(float4*)&P[m16][32 + g4 * 8 + 4];

        bf16x8 a0, a1;
        {
            float pv0[8] = {pa0.x, pa0.y, pa0.z, pa0.w, pa1.x, pa1.y, pa1.z, pa1.w};
            float pv1[8] = {pb0.x, pb0.y, pb0.z, pb0.w, pb1.x, pb1.y, pb1.z, pb1.w};
#pragma unroll
            for (int j = 0; j < 8; ++j) {
                a0[j] = f2b(pv0[j]);
                a1[j] = f2b(pv1[j]);
            }
        }

#pragma unroll
        for (int t = 0; t < 8; ++t) {
            const short* vp = vbase + (size_t)(t * 16 + m16) * Sq + kt + g4 * 8;
            bf16x8 v0 = *(const bf16x8*)(vp);
            bf16x8 v1 = *(const bf16x8*)(vp + 32);
            O[t] = __builtin_amdgcn_mfma_f32_16x16x32_bf16(a0, v0, O[t], 0, 0, 0);
            O[t] = __builtin_amdgcn_mfma_f32_16x16x32_bf16(a1, v1, O[t], 0, 0, 0);
        }
    }

    float inv[4];
#pragma unroll
    for (int i = 0; i < 4; ++i) inv[i] = 1.0f / lrow[i];

    short* op = AOb + ((size_t)b * Sq + q0) * (Hn * HDn) + h * HDn;
#pragma unroll
    for (int t = 0; t < 8; ++t)
#pragma unroll
        for (int i = 0; i < 4; ++i)
            op[(size_t)(g4 * 4 + i) * (Hn * HDn) + t * 16 + m16] = f2b(O[t][i] * inv[i]);
}

extern "C" void kernel_launch(void* const* d_in, const int* in_sizes, int n_in,
                              void* d_out, int out_size, void* d_ws, size_t ws_size,
                              hipStream_t stream)
{
    const float* x   = (const float*)d_in[0];
    const float* wq  = (const float*)d_in[1];
    const float* wk  = (const float*)d_in[2];
    const float* wv  = (const float*)d_in[3];
    const float* wo  = (const float*)d_in[4];
    const int* pos   = (const int*)d_in[6];
    float* out = (float*)d_out;

    const int M = Bsz * Sq;            // 4096
    const size_t nX  = (size_t)M * Dm; // 8388608

    short* xb    = (short*)d_ws;
    short* wqkvT = xb + nX;                       // 3072 x 2048
    short* woT   = wqkvT + (size_t)3072 * Dm;     // 2048 x 2048
    float* C3    = (float*)(woT + (size_t)Dm * Dm);
    short* Qb    = (short*)(C3 + (size_t)M * 3072);
    short* Kb    = Qb + nX;
    short* Vtb   = Kb + (size_t)Bsz * KVn * Sq * HDn;
    short* AOb   = Vtb + (size_t)Bsz * KVn * Sq * HDn;

    // --- conversions ---
    f2b_kernel<<<(nX / 4 + 255) / 256, 256, 0, stream>>>(x, xb, nX / 4);
    {
        dim3 blk(32, 8);
        wconvT_kernel<<<dim3(2048 / 32, Dm / 32), blk, 0, stream>>>(wq, wqkvT, 2048, 0);
        wconvT_kernel<<<dim3(512 / 32,  Dm / 32), blk, 0, stream>>>(wk, wqkvT, 512,  2048);
        wconvT_kernel<<<dim3(512 / 32,  Dm / 32), blk, 0, stream>>>(wv, wqkvT, 512,  2560);
        wconvT_kernel<<<dim3(2048 / 32, Dm / 32), blk, 0, stream>>>(wo, woT,   2048, 0);
    }

    // --- fused QKV projection: C3 (M x 3072) ---
    gemm_bt_kernel<<<dim3(3072 / 128, M / 128), 256, 0, stream>>>(
        xb, wqkvT, C3, M, 3072, Dm);

    // --- RoPE + split/convert ---
    {
        const float qscale = 0.08838834764831845f; // 1/sqrt(128)
        int totQ = Bsz * Hn * Sq * 64;
        rope_conv_kernel<<<(totQ + 255) / 256, 256, 0, stream>>>(
            C3, Qb, pos, Hn, 0, qscale, totQ);
        int totK = Bsz * KVn * Sq * 64;
        rope_conv_kernel<<<(totK + 255) / 256, 256, 0, stream>>>(
            C3, Kb, pos, KVn, 2048, 1.0f, totK);
    }
    vconv_kernel<<<dim3(Sq / 32, HDn / 32, Bsz * KVn), dim3(32, 8), 0, stream>>>(
        C3, Vtb);

    // --- attention ---
    fattn_kernel<<<Bsz * Hn * (Sq / 16), 64, 0, stream>>>(Qb, Kb, Vtb, AOb);

    // --- output projection ---
    gemm_bt_kernel<<<dim3(Dm / 128, M / 128), 256, 0, stream>>>(
        AOb, woT, out, M, Dm, Dm);
}

// Round 4
// 567.597 us; speedup vs baseline: 10.6678x; 1.1216x over previous
//
#include <hip/hip_runtime.h>
#include <hip/hip_bf16.h>
#include <math.h>

#define Bsz 2
#define Sq  2048
#define Dm  2048
#define Hn  16
#define KVn 4
#define HDn 128

typedef __attribute__((ext_vector_type(8))) short bf16x8;
typedef __attribute__((ext_vector_type(4))) float f32x4;

__device__ __forceinline__ short f2b(float f) {
    __hip_bfloat16 h = __float2bfloat16(f);
    return *reinterpret_cast<short*>(&h);
}

// ---------------- fp32 -> bf16 elementwise (x) ----------------
__global__ __launch_bounds__(256) void f2b_kernel(
    const float* __restrict__ X, short* __restrict__ Y, int n4)
{
    int i = blockIdx.x * 256 + threadIdx.x;
    if (i >= n4) return;
    float4 v = ((const float4*)X)[i];
    short4 o;
    o.x = f2b(v.x); o.y = f2b(v.y); o.z = f2b(v.z); o.w = f2b(v.w);
    ((short4*)Y)[i] = o;
}

// ------------- W (KxN fp32) -> Wt (NxK bf16), rows offset into fused buffer -------------
__global__ __launch_bounds__(256) void wconvT_kernel(
    const float* __restrict__ W, short* __restrict__ Wt, int N, int rowOff)
{
    __shared__ float t[32][33];
    const int k0 = blockIdx.y * 32;
    const int n0 = blockIdx.x * 32;
    const int tx = threadIdx.x, ty = threadIdx.y;
#pragma unroll
    for (int r = 0; r < 4; ++r) {
        const int row = ty + 8 * r;
        t[row][tx] = W[(size_t)(k0 + row) * N + n0 + tx];
    }
    __syncthreads();
#pragma unroll
    for (int r = 0; r < 4; ++r) {
        const int row = ty + 8 * r;
        Wt[(size_t)(rowOff + n0 + row) * Dm + k0 + tx] = f2b(t[tx][row]);
    }
}

// ---------------- bf16 MFMA GEMM: C(MxN fp32) = A(MxK) * Bt(NxK)^T ----------------
__global__ __launch_bounds__(256) void gemm_bt_kernel(
    const short* __restrict__ A, const short* __restrict__ Bt,
    float* __restrict__ C, int M, int N, int K)
{
    __shared__ __align__(16) short As[128 * 64];
    __shared__ __align__(16) short Bs[128 * 64];

    const int tid  = threadIdx.x;
    const int w    = tid >> 6;
    const int lane = tid & 63;
    const int m16  = lane & 15;
    const int g4   = lane >> 4;
    const int wm   = w >> 1, wn = w & 1;

    const int row0 = blockIdx.y * 128;
    const int col0 = blockIdx.x * 128;

    const short* Ab = A  + (size_t)row0 * K;
    const short* Bb = Bt + (size_t)col0 * K;

    const int trow = tid >> 3;
    const int soct = (tid & 7) ^ (trow & 7);

    f32x4 acc[4][4];
#pragma unroll
    for (int i = 0; i < 4; ++i)
#pragma unroll
        for (int j = 0; j < 4; ++j) acc[i][j] = (f32x4){0.f, 0.f, 0.f, 0.f};

    for (int k0 = 0; k0 < K; k0 += 64) {
#pragma unroll
        for (int r = 0; r < 4; ++r) {
            const short* gp = Ab + (size_t)(r * 32 + trow) * K + k0 + soct * 8;
            short* lp = &As[(size_t)(r * 256 + w * 64) * 8];
            __builtin_amdgcn_global_load_lds(
                (const __attribute__((address_space(1))) void*)gp,
                (__attribute__((address_space(3))) void*)lp, 16, 0, 0);
        }
#pragma unroll
        for (int r = 0; r < 4; ++r) {
            const short* gp = Bb + (size_t)(r * 32 + trow) * K + k0 + soct * 8;
            short* lp = &Bs[(size_t)(r * 256 + w * 64) * 8];
            __builtin_amdgcn_global_load_lds(
                (const __attribute__((address_space(1))) void*)gp,
                (__attribute__((address_space(3))) void*)lp, 16, 0, 0);
        }
        __syncthreads();

#pragma unroll
        for (int kc = 0; kc < 2; ++kc) {
            bf16x8 a[4], b[4];
            const int swz = (kc * 4 + g4) ^ (m16 & 7);
#pragma unroll
            for (int s = 0; s < 4; ++s) {
                const int rowA = wm * 64 + s * 16 + m16;
                a[s] = *(const bf16x8*)&As[rowA * 64 + swz * 8];
                const int rowB = wn * 64 + s * 16 + m16;
                b[s] = *(const bf16x8*)&Bs[rowB * 64 + swz * 8];
            }
#pragma unroll
            for (int i = 0; i < 4; ++i)
#pragma unroll
                for (int j = 0; j < 4; ++j)
                    acc[i][j] = __builtin_amdgcn_mfma_f32_16x16x32_bf16(
                        a[i], b[j], acc[i][j], 0, 0, 0);
        }
        __syncthreads();
    }

#pragma unroll
    for (int i = 0; i < 4; ++i) {
        const int mbase = row0 + wm * 64 + i * 16 + g4 * 4;
#pragma unroll
        for (int j = 0; j < 4; ++j) {
            const int n = col0 + wn * 64 + j * 16 + m16;
#pragma unroll
            for (int r = 0; r < 4; ++r)
                C[(size_t)(mbase + r) * N + n] = acc[i][j][r];
        }
    }
}

// ------------- RoPE from C3 (B,S,3072) fp32 -> bf16 split layout -------------
__global__ __launch_bounds__(256) void rope_conv_kernel(
    const float* __restrict__ C3, short* __restrict__ Y,
    const int* __restrict__ pos_ids, int NHx, int colOff, float scale, int total)
{
    int idx = blockIdx.x * blockDim.x + threadIdx.x;
    if (idx >= total) return;
    const int i = idx & 63;
    int rest = idx >> 6;
    const int s = rest % Sq; rest /= Sq;
    const int h = rest % NHx;
    const int b = rest / NHx;

    const int pos = pos_ids[b * Sq + s];
    const float e   = -(float)(2 * i) * (1.0f / (float)HDn);
    const float inv = powf(500000.0f, e);
    const float f   = (float)pos * inv;
    const float c   = cosf(f);
    const float sn  = sinf(f);

    const float* src = C3 + ((size_t)(b * Sq + s)) * 3072 + colOff + h * HDn;
    const float x1 = src[i];
    const float x2 = src[i + 64];
    const size_t dst = (((size_t)b * NHx + h) * Sq + s) * HDn;
    Y[dst + i]      = f2b((x1 * c - x2 * sn) * scale);
    Y[dst + i + 64] = f2b((x2 * c + x1 * sn) * scale);
}

// ------------- V region of C3 -> bf16 transposed (B,KV,HD,S) -------------
__global__ __launch_bounds__(256) void vconv_kernel(
    const float* __restrict__ C3, short* __restrict__ Vt)
{
    __shared__ float t[32][33];
    const int bk = blockIdx.z;
    const int b  = bk >> 2, kv = bk & 3;
    const int s0 = blockIdx.x * 32;
    const int d0 = blockIdx.y * 32;
    const int tx = threadIdx.x, ty = threadIdx.y;

#pragma unroll
    for (int r = 0; r < 4; ++r) {
        const int row = ty + 8 * r;
        t[row][tx] = C3[((size_t)(b * Sq + s0 + row)) * 3072 + 2560 + kv * HDn + d0 + tx];
    }
    __syncthreads();
#pragma unroll
    for (int r = 0; r < 4; ++r) {
        const int row = ty + 8 * r;
        Vt[((size_t)bk * HDn + d0 + row) * Sq + s0 + tx] = f2b(t[tx][row]);
    }
}

// ------------- Block-cooperative MFMA flash attention -------------
// 256 threads = 4 waves, 64 q-rows per block (16 per wave), 64-key chunks
// staged in LDS and shared by all 4 waves.
// Qb: (B,H,S,HD) bf16 pre-scaled by log2(e)/sqrt(HD). Kb: (B,KV,S,HD) bf16.
// Vtb: (B,KV,HD,S) bf16. AOb: (B,S,H*HD) bf16.
__global__ __launch_bounds__(256) void fattn_kernel(
    const short* __restrict__ Qb, const short* __restrict__ Kb,
    const short* __restrict__ Vtb, short* __restrict__ AOb)
{
    __shared__ __align__(16) short Ks[64 * 128];   // [key][dim], oct-swizzled
    __shared__ __align__(16) short Vs[128 * 64];   // [dim][key], oct-swizzled
    __shared__ float P[4][16][68];

    const int tid  = threadIdx.x;
    const int w    = tid >> 6;
    const int lane = tid & 63;
    const int m16  = lane & 15;
    const int g4   = lane >> 4;

    const int qblk = blockIdx.x & 31;       // S/64 = 32 q-tiles per head
    const int bh   = blockIdx.x >> 5;
    const int h    = bh & 15;
    const int b    = bh >> 4;
    const int kv   = h >> 2;
    const int q0   = qblk << 6;
    const int qw0  = q0 + w * 16;

    const short* qp = Qb + (((size_t)b * Hn + h) * Sq + qw0 + m16) * HDn + g4 * 8;
    bf16x8 qf[4];
#pragma unroll
    for (int c = 0; c < 4; ++c) qf[c] = *(const bf16x8*)(qp + c * 32);

    const short* kbase = Kb  + ((size_t)b * KVn + kv) * Sq * HDn;
    const short* vbase = Vtb + ((size_t)b * KVn + kv) * (size_t)HDn * Sq;

    f32x4 O[8];
#pragma unroll
    for (int t = 0; t < 8; ++t) O[t] = (f32x4){0.f, 0.f, 0.f, 0.f};
    float mrow[4] = {-1e30f, -1e30f, -1e30f, -1e30f};
    float lrow[4] = {0.f, 0.f, 0.f, 0.f};

    const int nch = qblk + 1;
    for (int ch = 0; ch < nch; ++ch) {
        const int kt = ch << 6;

        // ---- stage K tile: 64 keys x 128 dims (16 octs/row, oct-swizzled) ----
        {
            const short* kg = kbase + (size_t)kt * HDn;
#pragma unroll
            for (int r = 0; r < 4; ++r) {
                const int c = r * 256 + tid;
                const int key = c >> 4, oct = c & 15;
                const short* gp = kg + key * HDn + (oct ^ (key & 7)) * 8;
                short* lp = &Ks[(size_t)(r * 256 + w * 64) * 8];
                __builtin_amdgcn_global_load_lds(
                    (const __attribute__((address_space(1))) void*)gp,
                    (__attribute__((address_space(3))) void*)lp, 16, 0, 0);
            }
            // ---- stage Vt tile: 128 dims x 64 keys (8 octs/row, oct-swizzled) ----
#pragma unroll
            for (int r = 0; r < 4; ++r) {
                const int c = r * 256 + tid;
                const int d = c >> 3, oct = c & 7;
                const short* gp = vbase + (size_t)d * Sq + kt + (oct ^ (d & 7)) * 8;
                short* lp = &Vs[(size_t)(r * 256 + w * 64) * 8];
                __builtin_amdgcn_global_load_lds(
                    (const __attribute__((address_space(1))) void*)gp,
                    (__attribute__((address_space(3))) void*)lp, 16, 0, 0);
            }
        }
        __syncthreads();

        // ---- scores: QK^T from LDS ----
        f32x4 sc[4];
#pragma unroll
        for (int f = 0; f < 4; ++f) {
            f32x4 acc = (f32x4){0.f, 0.f, 0.f, 0.f};
            const int krow = f * 16 + m16;
#pragma unroll
            for (int c = 0; c < 4; ++c) {
                bf16x8 kf = *(const bf16x8*)&Ks[krow * 128 + ((c * 4 + g4) ^ (m16 & 7)) * 8];
                acc = __builtin_amdgcn_mfma_f32_16x16x32_bf16(qf[c], kf, acc, 0, 0, 0);
            }
            sc[f] = acc;
        }

        if (ch == qblk) {  // diagonal chunk: causal mask
#pragma unroll
            for (int f = 0; f < 4; ++f)
#pragma unroll
                for (int i = 0; i < 4; ++i) {
                    const int kg = kt + f * 16 + m16;
                    const int qg = qw0 + g4 * 4 + i;
                    if (kg > qg) sc[f][i] = -1e30f;
                }
        }

        // ---- online softmax (base-2; log2e folded into Q scale) ----
        float alpha[4];
#pragma unroll
        for (int i = 0; i < 4; ++i) {
            float mx = fmaxf(fmaxf(sc[0][i], sc[1][i]), fmaxf(sc[2][i], sc[3][i]));
            mx = fmaxf(mx, __shfl_xor(mx, 1));
            mx = fmaxf(mx, __shfl_xor(mx, 2));
            mx = fmaxf(mx, __shfl_xor(mx, 4));
            mx = fmaxf(mx, __shfl_xor(mx, 8));
            const float nm = fmaxf(mrow[i], mx);
            alpha[i] = exp2f(mrow[i] - nm);
            mrow[i]  = nm;
            float ps = 0.f;
#pragma unroll
            for (int f = 0; f < 4; ++f) {
                sc[f][i] = exp2f(sc[f][i] - nm);
                ps += sc[f][i];
            }
            ps += __shfl_xor(ps, 1);
            ps += __shfl_xor(ps, 2);
            ps += __shfl_xor(ps, 4);
            ps += __shfl_xor(ps, 8);
            lrow[i] = lrow[i] * alpha[i] + ps;
        }

#pragma unroll
        for (int t = 0; t < 8; ++t)
#pragma unroll
            for (int i = 0; i < 4; ++i) O[t][i] *= alpha[i];

        // ---- P: C-layout -> LDS -> A-layout (per wave) ----
#pragma unroll
        for (int f = 0; f < 4; ++f)
#pragma unroll
            for (int i = 0; i < 4; ++i)
                P[w][g4 * 4 + i][f * 16 + m16] = sc[f][i];

        float4 pa0 = *(float4*)&P[w][m16][g4 * 8];
        float4 pa1 = *(float4*)&P[w][m16][g4 * 8 + 4];
        float4 pb0 = *(float4*)&P[w][m16][32 + g4 * 8];
        float4 pb1 = *(float4*)&P[w][m16][32 + g4 * 8 + 4];

        bf16x8 a0, a1;
        {
            float pv0[8] = {pa0.x, pa0.y, pa0.z, pa0.w, pa1.x, pa1.y, pa1.z, pa1.w};
            float pv1[8] = {pb0.x, pb0.y, pb0.z, pb0.w, pb1.x, pb1.y, pb1.z, pb1.w};
#pragma unroll
            for (int j = 0; j < 8; ++j) {
                a0[j] = f2b(pv0[j]);
                a1[j] = f2b(pv1[j]);
            }
        }

        // ---- PV from LDS Vt tile ----
#pragma unroll
        for (int t = 0; t < 8; ++t) {
            const int vrow = t * 16 + m16;
            bf16x8 v0 = *(const bf16x8*)&Vs[vrow * 64 + ((g4)     ^ (m16 & 7)) * 8];
            bf16x8 v1 = *(const bf16x8*)&Vs[vrow * 64 + ((4 + g4) ^ (m16 & 7)) * 8];
            O[t] = __builtin_amdgcn_mfma_f32_16x16x32_bf16(a0, v0, O[t], 0, 0, 0);
            O[t] = __builtin_amdgcn_mfma_f32_16x16x32_bf16(a1, v1, O[t], 0, 0, 0);
        }
        __syncthreads();
    }

    float inv[4];
#pragma unroll
    for (int i = 0; i < 4; ++i) inv[i] = 1.0f / lrow[i];

    short* op = AOb + ((size_t)b * Sq + qw0) * (Hn * HDn) + h * HDn;
#pragma unroll
    for (int t = 0; t < 8; ++t)
#pragma unroll
        for (int i = 0; i < 4; ++i)
            op[(size_t)(g4 * 4 + i) * (Hn * HDn) + t * 16 + m16] = f2b(O[t][i] * inv[i]);
}

extern "C" void kernel_launch(void* const* d_in, const int* in_sizes, int n_in,
                              void* d_out, int out_size, void* d_ws, size_t ws_size,
                              hipStream_t stream)
{
    const float* x   = (const float*)d_in[0];
    const float* wq  = (const float*)d_in[1];
    const float* wk  = (const float*)d_in[2];
    const float* wv  = (const float*)d_in[3];
    const float* wo  = (const float*)d_in[4];
    const int* pos   = (const int*)d_in[6];
    float* out = (float*)d_out;

    const int M = Bsz * Sq;            // 4096
    const size_t nX  = (size_t)M * Dm; // 8388608

    short* xb    = (short*)d_ws;
    short* wqkvT = xb + nX;                       // 3072 x 2048
    short* woT   = wqkvT + (size_t)3072 * Dm;     // 2048 x 2048
    float* C3    = (float*)(woT + (size_t)Dm * Dm);
    short* Qb    = (short*)(C3 + (size_t)M * 3072);
    short* Kb    = Qb + nX;
    short* Vtb   = Kb + (size_t)Bsz * KVn * Sq * HDn;
    short* AOb   = Vtb + (size_t)Bsz * KVn * Sq * HDn;

    // --- conversions ---
    f2b_kernel<<<(nX / 4 + 255) / 256, 256, 0, stream>>>(x, xb, nX / 4);
    {
        dim3 blk(32, 8);
        wconvT_kernel<<<dim3(2048 / 32, Dm / 32), blk, 0, stream>>>(wq, wqkvT, 2048, 0);
        wconvT_kernel<<<dim3(512 / 32,  Dm / 32), blk, 0, stream>>>(wk, wqkvT, 512,  2048);
        wconvT_kernel<<<dim3(512 / 32,  Dm / 32), blk, 0, stream>>>(wv, wqkvT, 512,  2560);
        wconvT_kernel<<<dim3(2048 / 32, Dm / 32), blk, 0, stream>>>(wo, woT,   2048, 0);
    }

    // --- fused QKV projection: C3 (M x 3072) ---
    gemm_bt_kernel<<<dim3(3072 / 128, M / 128), 256, 0, stream>>>(
        xb, wqkvT, C3, M, 3072, Dm);

    // --- RoPE + split/convert ---
    {
        // 1/sqrt(128) * log2(e): base-2 softmax
        const float qscale = 0.08838834764831845f * 1.4426950408889634f;
        int totQ = Bsz * Hn * Sq * 64;
        rope_conv_kernel<<<(totQ + 255) / 256, 256, 0, stream>>>(
            C3, Qb, pos, Hn, 0, qscale, totQ);
        int totK = Bsz * KVn * Sq * 64;
        rope_conv_kernel<<<(totK + 255) / 256, 256, 0, stream>>>(
            C3, Kb, pos, KVn, 2048, 1.0f, totK);
    }
    vconv_kernel<<<dim3(Sq / 32, HDn / 32, Bsz * KVn), dim3(32, 8), 0, stream>>>(
        C3, Vtb);

    // --- attention: one block per 64 q-rows ---
    fattn_kernel<<<Bsz * Hn * (Sq / 64), 256, 0, stream>>>(Qb, Kb, Vtb, AOb);

    // --- output projection ---
    gemm_bt_kernel<<<dim3(Dm / 128, M / 128), 256, 0, stream>>>(
        AOb, woT, out, M, Dm, Dm);
}

// Round 5
// 529.494 us; speedup vs baseline: 11.4355x; 1.0720x over previous
//
#include <hip/hip_runtime.h>
#include <hip/hip_bf16.h>
#include <math.h>

#define Bsz 2
#define Sq  2048
#define Dm  2048
#define Hn  16
#define KVn 4
#define HDn 128

typedef __attribute__((ext_vector_type(8))) short bf16x8;
typedef __attribute__((ext_vector_type(4))) short bf16x4;
typedef __attribute__((ext_vector_type(4))) float f32x4;

__device__ __forceinline__ short f2b(float f) {
    __hip_bfloat16 h = __float2bfloat16(f);
    return *reinterpret_cast<short*>(&h);
}

// ---------------- fp32 -> bf16 elementwise (x) ----------------
__global__ __launch_bounds__(256) void f2b_kernel(
    const float* __restrict__ X, short* __restrict__ Y, int n4)
{
    int i = blockIdx.x * 256 + threadIdx.x;
    if (i >= n4) return;
    float4 v = ((const float4*)X)[i];
    short4 o;
    o.x = f2b(v.x); o.y = f2b(v.y); o.z = f2b(v.z); o.w = f2b(v.w);
    ((short4*)Y)[i] = o;
}

// ------------- W (KxN fp32) -> Wt (NxK bf16), rows offset into fused buffer -------------
__global__ __launch_bounds__(256) void wconvT_kernel(
    const float* __restrict__ W, short* __restrict__ Wt, int N, int rowOff)
{
    __shared__ float t[32][33];
    const int k0 = blockIdx.y * 32;
    const int n0 = blockIdx.x * 32;
    const int tx = threadIdx.x, ty = threadIdx.y;
#pragma unroll
    for (int r = 0; r < 4; ++r) {
        const int row = ty + 8 * r;
        t[row][tx] = W[(size_t)(k0 + row) * N + n0 + tx];
    }
    __syncthreads();
#pragma unroll
    for (int r = 0; r < 4; ++r) {
        const int row = ty + 8 * r;
        Wt[(size_t)(rowOff + n0 + row) * Dm + k0 + tx] = f2b(t[tx][row]);
    }
}

// ---------------- bf16 MFMA GEMM: C(MxN fp32) = A(MxK) * Bt(NxK)^T ----------------
__global__ __launch_bounds__(256) void gemm_bt_kernel(
    const short* __restrict__ A, const short* __restrict__ Bt,
    float* __restrict__ C, int M, int N, int K)
{
    __shared__ __align__(16) short As[128 * 64];
    __shared__ __align__(16) short Bs[128 * 64];

    const int tid  = threadIdx.x;
    const int w    = tid >> 6;
    const int lane = tid & 63;
    const int m16  = lane & 15;
    const int g4   = lane >> 4;
    const int wm   = w >> 1, wn = w & 1;

    const int row0 = blockIdx.y * 128;
    const int col0 = blockIdx.x * 128;

    const short* Ab = A  + (size_t)row0 * K;
    const short* Bb = Bt + (size_t)col0 * K;

    const int trow = tid >> 3;
    const int soct = (tid & 7) ^ (trow & 7);

    f32x4 acc[4][4];
#pragma unroll
    for (int i = 0; i < 4; ++i)
#pragma unroll
        for (int j = 0; j < 4; ++j) acc[i][j] = (f32x4){0.f, 0.f, 0.f, 0.f};

    for (int k0 = 0; k0 < K; k0 += 64) {
#pragma unroll
        for (int r = 0; r < 4; ++r) {
            const short* gp = Ab + (size_t)(r * 32 + trow) * K + k0 + soct * 8;
            short* lp = &As[(size_t)(r * 256 + w * 64) * 8];
            __builtin_amdgcn_global_load_lds(
                (const __attribute__((address_space(1))) void*)gp,
                (__attribute__((address_space(3))) void*)lp, 16, 0, 0);
        }
#pragma unroll
        for (int r = 0; r < 4; ++r) {
            const short* gp = Bb + (size_t)(r * 32 + trow) * K + k0 + soct * 8;
            short* lp = &Bs[(size_t)(r * 256 + w * 64) * 8];
            __builtin_amdgcn_global_load_lds(
                (const __attribute__((address_space(1))) void*)gp,
                (__attribute__((address_space(3))) void*)lp, 16, 0, 0);
        }
        __syncthreads();

#pragma unroll
        for (int kc = 0; kc < 2; ++kc) {
            bf16x8 a[4], b[4];
            const int swz = (kc * 4 + g4) ^ (m16 & 7);
#pragma unroll
            for (int s = 0; s < 4; ++s) {
                const int rowA = wm * 64 + s * 16 + m16;
                a[s] = *(const bf16x8*)&As[rowA * 64 + swz * 8];
                const int rowB = wn * 64 + s * 16 + m16;
                b[s] = *(const bf16x8*)&Bs[rowB * 64 + swz * 8];
            }
#pragma unroll
            for (int i = 0; i < 4; ++i)
#pragma unroll
                for (int j = 0; j < 4; ++j)
                    acc[i][j] = __builtin_amdgcn_mfma_f32_16x16x32_bf16(
                        a[i], b[j], acc[i][j], 0, 0, 0);
        }
        __syncthreads();
    }

#pragma unroll
    for (int i = 0; i < 4; ++i) {
        const int mbase = row0 + wm * 64 + i * 16 + g4 * 4;
#pragma unroll
        for (int j = 0; j < 4; ++j) {
            const int n = col0 + wn * 64 + j * 16 + m16;
#pragma unroll
            for (int r = 0; r < 4; ++r)
                C[(size_t)(mbase + r) * N + n] = acc[i][j][r];
        }
    }
}

// ------------- RoPE from C3 (B,S,3072) fp32 -> bf16 split layout -------------
__global__ __launch_bounds__(256) void rope_conv_kernel(
    const float* __restrict__ C3, short* __restrict__ Y,
    const int* __restrict__ pos_ids, int NHx, int colOff, float scale, int total)
{
    int idx = blockIdx.x * blockDim.x + threadIdx.x;
    if (idx >= total) return;
    const int i = idx & 63;
    int rest = idx >> 6;
    const int s = rest % Sq; rest /= Sq;
    const int h = rest % NHx;
    const int b = rest / NHx;

    const int pos = pos_ids[b * Sq + s];
    const float e   = -(float)(2 * i) * (1.0f / (float)HDn);
    const float inv = powf(500000.0f, e);
    const float f   = (float)pos * inv;
    const float c   = cosf(f);
    const float sn  = sinf(f);

    const float* src = C3 + ((size_t)(b * Sq + s)) * 3072 + colOff + h * HDn;
    const float x1 = src[i];
    const float x2 = src[i + 64];
    const size_t dst = (((size_t)b * NHx + h) * Sq + s) * HDn;
    Y[dst + i]      = f2b((x1 * c - x2 * sn) * scale);
    Y[dst + i + 64] = f2b((x2 * c + x1 * sn) * scale);
}

// ------------- V region of C3 -> bf16 transposed (B,KV,HD,S) -------------
__global__ __launch_bounds__(256) void vconv_kernel(
    const float* __restrict__ C3, short* __restrict__ Vt)
{
    __shared__ float t[32][33];
    const int bk = blockIdx.z;
    const int b  = bk >> 2, kv = bk & 3;
    const int s0 = blockIdx.x * 32;
    const int d0 = blockIdx.y * 32;
    const int tx = threadIdx.x, ty = threadIdx.y;

#pragma unroll
    for (int r = 0; r < 4; ++r) {
        const int row = ty + 8 * r;
        t[row][tx] = C3[((size_t)(b * Sq + s0 + row)) * 3072 + 2560 + kv * HDn + d0 + tx];
    }
    __syncthreads();
#pragma unroll
    for (int r = 0; r < 4; ++r) {
        const int row = ty + 8 * r;
        Vt[((size_t)bk * HDn + d0 + row) * Sq + s0 + tx] = f2b(t[tx][row]);
    }
}

// ------------- Block-cooperative MFMA flash attention, KQ orientation -------------
// S = K*Q^T  (C-layout: col=query in lane&15, rows=keys in regs) so softmax is
// in-lane + 2 shuffles, and the exp'd P tile is directly a B-fragment for
// mfma_16x16x16 (PV computed as O^T = V^T * P). No P LDS round-trip.
// Qb: (B,H,S,HD) bf16 pre-scaled by log2(e)/sqrt(HD). Kb: (B,KV,S,HD) bf16.
// Vtb: (B,KV,HD,S) bf16. AOb: (B,S,H*HD) bf16.
__global__ __launch_bounds__(256) void fattn_kernel(
    const short* __restrict__ Qb, const short* __restrict__ Kb,
    const short* __restrict__ Vtb, short* __restrict__ AOb)
{
    __shared__ __align__(16) short Ks[64 * 128];   // [key][dim], oct-swizzled
    __shared__ __align__(16) short Vs[128 * 64];   // [dim][key], oct-swizzled

    const int tid  = threadIdx.x;
    const int w    = tid >> 6;
    const int lane = tid & 63;
    const int m16  = lane & 15;
    const int g4   = lane >> 4;

    const int qblk = blockIdx.x & 31;       // S/64 = 32 q-tiles per head
    const int bh   = blockIdx.x >> 5;
    const int h    = bh & 15;
    const int b    = bh >> 4;
    const int kv   = h >> 2;
    const int qw0  = (qblk << 6) + w * 16;  // this wave's 16 queries

    // Q as B-operand: B[k=dim g4*8+j][n=query m16]
    const short* qp = Qb + (((size_t)b * Hn + h) * Sq + qw0 + m16) * HDn + g4 * 8;
    bf16x8 qf[4];
#pragma unroll
    for (int c = 0; c < 4; ++c) qf[c] = *(const bf16x8*)(qp + c * 32);

    const short* kbase = Kb  + ((size_t)b * KVn + kv) * Sq * HDn;
    const short* vbase = Vtb + ((size_t)b * KVn + kv) * (size_t)HDn * Sq;

    // O^T accumulator: Ot[t][i] = dim t*16+g4*4+i, query m16
    f32x4 Ot[8];
#pragma unroll
    for (int t = 0; t < 8; ++t) Ot[t] = (f32x4){0.f, 0.f, 0.f, 0.f};
    float mcur = -1e30f, lcur = 0.f;

    const int nch = qblk + 1;
    for (int ch = 0; ch < nch; ++ch) {
        const int kt = ch << 6;

        // ---- stage K tile: 64 keys x 128 dims (oct-swizzled by key&7) ----
        {
            const short* kg = kbase + (size_t)kt * HDn;
#pragma unroll
            for (int r = 0; r < 4; ++r) {
                const int c = r * 256 + tid;
                const int key = c >> 4, oct = c & 15;
                const short* gp = kg + key * HDn + (oct ^ (key & 7)) * 8;
                short* lp = &Ks[(size_t)(r * 256 + w * 64) * 8];
                __builtin_amdgcn_global_load_lds(
                    (const __attribute__((address_space(1))) void*)gp,
                    (__attribute__((address_space(3))) void*)lp, 16, 0, 0);
            }
            // ---- stage Vt tile: 128 dims x 64 keys (oct-swizzled by dim&7) ----
#pragma unroll
            for (int r = 0; r < 4; ++r) {
                const int c = r * 256 + tid;
                const int d = c >> 3, oct = c & 7;
                const short* gp = vbase + (size_t)d * Sq + kt + (oct ^ (d & 7)) * 8;
                short* lp = &Vs[(size_t)(r * 256 + w * 64) * 8];
                __builtin_amdgcn_global_load_lds(
                    (const __attribute__((address_space(1))) void*)gp,
                    (__attribute__((address_space(3))) void*)lp, 16, 0, 0);
            }
        }
        __syncthreads();

        // ---- scores S[key][query]: A = K-frag, B = Q-frag ----
        f32x4 sc[4];
#pragma unroll
        for (int f = 0; f < 4; ++f) {
            f32x4 acc = (f32x4){0.f, 0.f, 0.f, 0.f};
            const int krow = f * 16 + m16;
#pragma unroll
            for (int c = 0; c < 4; ++c) {
                bf16x8 kf = *(const bf16x8*)&Ks[krow * 128 + ((c * 4 + g4) ^ (m16 & 7)) * 8];
                acc = __builtin_amdgcn_mfma_f32_16x16x32_bf16(kf, qf[c], acc, 0, 0, 0);
            }
            sc[f] = acc;
        }

        if (ch == qblk) {  // diagonal chunk: causal mask. key rows, query cols.
            const int qg = qw0 + m16;
#pragma unroll
            for (int f = 0; f < 4; ++f)
#pragma unroll
                for (int i = 0; i < 4; ++i) {
                    const int kg = kt + f * 16 + g4 * 4 + i;
                    if (kg > qg) sc[f][i] = -1e30f;
                }
        }

        // ---- online softmax: in-lane over 16 regs + 2 shuffles across quads ----
        float mx = sc[0][0];
#pragma unroll
        for (int f = 0; f < 4; ++f)
#pragma unroll
            for (int i = 0; i < 4; ++i) mx = fmaxf(mx, sc[f][i]);
        mx = fmaxf(mx, __shfl_xor(mx, 16));
        mx = fmaxf(mx, __shfl_xor(mx, 32));
        const float nm = fmaxf(mcur, mx);
        const float alpha = exp2f(mcur - nm);
        mcur = nm;
        float ps = 0.f;
#pragma unroll
        for (int f = 0; f < 4; ++f)
#pragma unroll
            for (int i = 0; i < 4; ++i) {
                sc[f][i] = exp2f(sc[f][i] - nm);
                ps += sc[f][i];
            }
        ps += __shfl_xor(ps, 16);
        ps += __shfl_xor(ps, 32);
        lcur = lcur * alpha + ps;

#pragma unroll
        for (int t = 0; t < 8; ++t)
#pragma unroll
            for (int i = 0; i < 4; ++i) Ot[t][i] *= alpha;

        // ---- P subtiles are B-frags for mfma_16x16x16 (k=g4*4+i, n=m16) ----
        bf16x4 pf[4];
#pragma unroll
        for (int f = 0; f < 4; ++f) {
            bf16x4 p;
#pragma unroll
            for (int i = 0; i < 4; ++i) p[i] = f2b(sc[f][i]);
            pf[f] = p;
        }

        // ---- PV: O^T[d][q] += V^T[d][k] * P[k][q] ----
#pragma unroll
        for (int t = 0; t < 8; ++t) {
            const int d = t * 16 + m16;
            f32x4 acc = Ot[t];
#pragma unroll
            for (int f = 0; f < 4; ++f) {
                const int oct = f * 2 + (g4 >> 1);
                const bf16x4 vf = *(const bf16x4*)&Vs[d * 64 +
                    ((oct ^ (m16 & 7)) * 8 + (g4 & 1) * 4)];
                acc = __builtin_amdgcn_mfma_f32_16x16x16bf16_1k(vf, pf[f], acc, 0, 0, 0);
            }
            Ot[t] = acc;
        }
        __syncthreads();
    }

    // ---- epilogue: O^T / l -> AOb (B,S,H*HD) bf16 ----
    const float inv = 1.0f / lcur;
    short* op = AOb + ((size_t)b * Sq + qw0 + m16) * (Hn * HDn) + h * HDn + g4 * 4;
#pragma unroll
    for (int t = 0; t < 8; ++t) {
        short4 o;
        o.x = f2b(Ot[t][0] * inv);
        o.y = f2b(Ot[t][1] * inv);
        o.z = f2b(Ot[t][2] * inv);
        o.w = f2b(Ot[t][3] * inv);
        *(short4*)(op + t * 16) = o;
    }
}

extern "C" void kernel_launch(void* const* d_in, const int* in_sizes, int n_in,
                              void* d_out, int out_size, void* d_ws, size_t ws_size,
                              hipStream_t stream)
{
    const float* x   = (const float*)d_in[0];
    const float* wq  = (const float*)d_in[1];
    const float* wk  = (const float*)d_in[2];
    const float* wv  = (const float*)d_in[3];
    const float* wo  = (const float*)d_in[4];
    const int* pos   = (const int*)d_in[6];
    float* out = (float*)d_out;

    const int M = Bsz * Sq;            // 4096
    const size_t nX  = (size_t)M * Dm; // 8388608

    short* xb    = (short*)d_ws;
    short* wqkvT = xb + nX;                       // 3072 x 2048
    short* woT   = wqkvT + (size_t)3072 * Dm;     // 2048 x 2048
    float* C3    = (float*)(woT + (size_t)Dm * Dm);
    short* Qb    = (short*)(C3 + (size_t)M * 3072);
    short* Kb    = Qb + nX;
    short* Vtb   = Kb + (size_t)Bsz * KVn * Sq * HDn;
    short* AOb   = Vtb + (size_t)Bsz * KVn * Sq * HDn;

    // --- conversions ---
    f2b_kernel<<<(nX / 4 + 255) / 256, 256, 0, stream>>>(x, xb, nX / 4);
    {
        dim3 blk(32, 8);
        wconvT_kernel<<<dim3(2048 / 32, Dm / 32), blk, 0, stream>>>(wq, wqkvT, 2048, 0);
        wconvT_kernel<<<dim3(512 / 32,  Dm / 32), blk, 0, stream>>>(wk, wqkvT, 512,  2048);
        wconvT_kernel<<<dim3(512 / 32,  Dm / 32), blk, 0, stream>>>(wv, wqkvT, 512,  2560);
        wconvT_kernel<<<dim3(2048 / 32, Dm / 32), blk, 0, stream>>>(wo, woT,   2048, 0);
    }

    // --- fused QKV projection: C3 (M x 3072) ---
    gemm_bt_kernel<<<dim3(3072 / 128, M / 128), 256, 0, stream>>>(
        xb, wqkvT, C3, M, 3072, Dm);

    // --- RoPE + split/convert ---
    {
        // 1/sqrt(128) * log2(e): base-2 softmax
        const float qscale = 0.08838834764831845f * 1.4426950408889634f;
        int totQ = Bsz * Hn * Sq * 64;
        rope_conv_kernel<<<(totQ + 255) / 256, 256, 0, stream>>>(
            C3, Qb, pos, Hn, 0, qscale, totQ);
        int totK = Bsz * KVn * Sq * 64;
        rope_conv_kernel<<<(totK + 255) / 256, 256, 0, stream>>>(
            C3, Kb, pos, KVn, 2048, 1.0f, totK);
    }
    vconv_kernel<<<dim3(Sq / 32, HDn / 32, Bsz * KVn), dim3(32, 8), 0, stream>>>(
        C3, Vtb);

    // --- attention: one block per 64 q-rows ---
    fattn_kernel<<<Bsz * Hn * (Sq / 64), 256, 0, stream>>>(Qb, Kb, Vtb, AOb);

    // --- output projection ---
    gemm_bt_kernel<<<dim3(Dm / 128, M / 128), 256, 0, stream>>>(
        AOb, woT, out, M, Dm, Dm);
}

// Round 6
// 376.739 us; speedup vs baseline: 16.0722x; 1.4055x over previous
//
#include <hip/hip_runtime.h>
#include <hip/hip_bf16.h>
#include <math.h>

#define Bsz 2
#define Sq  2048
#define Dm  2048
#define Hn  16
#define KVn 4
#define HDn 128

typedef __attribute__((ext_vector_type(8))) short bf16x8;
typedef __attribute__((ext_vector_type(4))) float f32x4;

__device__ __forceinline__ short f2b(float f) {
    __hip_bfloat16 h = __float2bfloat16(f);
    return *reinterpret_cast<short*>(&h);
}

// ---------------- fp32 -> bf16 elementwise (x) ----------------
__global__ __launch_bounds__(256) void f2b_kernel(
    const float* __restrict__ X, short* __restrict__ Y, int n4)
{
    int i = blockIdx.x * 256 + threadIdx.x;
    if (i >= n4) return;
    float4 v = ((const float4*)X)[i];
    short4 o;
    o.x = f2b(v.x); o.y = f2b(v.y); o.z = f2b(v.z); o.w = f2b(v.w);
    ((short4*)Y)[i] = o;
}

// ------------- W (KxN fp32) -> Wt (NxK bf16), rows offset into fused buffer -------------
__global__ __launch_bounds__(256) void wconvT_kernel(
    const float* __restrict__ W, short* __restrict__ Wt, int N, int rowOff)
{
    __shared__ float t[32][33];
    const int k0 = blockIdx.y * 32;
    const int n0 = blockIdx.x * 32;
    const int tx = threadIdx.x, ty = threadIdx.y;
#pragma unroll
    for (int r = 0; r < 4; ++r) {
        const int row = ty + 8 * r;
        t[row][tx] = W[(size_t)(k0 + row) * N + n0 + tx];
    }
    __syncthreads();
#pragma unroll
    for (int r = 0; r < 4; ++r) {
        const int row = ty + 8 * r;
        Wt[(size_t)(rowOff + n0 + row) * Dm + k0 + tx] = f2b(t[tx][row]);
    }
}

// ---------------- bf16 MFMA GEMM: C(MxN fp32) = A(MxK) * Bt(NxK)^T ----------------
__global__ __launch_bounds__(256) void gemm_bt_kernel(
    const short* __restrict__ A, const short* __restrict__ Bt,
    float* __restrict__ C, int M, int N, int K)
{
    __shared__ __align__(16) short As[128 * 64];
    __shared__ __align__(16) short Bs[128 * 64];

    const int tid  = threadIdx.x;
    const int w    = tid >> 6;
    const int lane = tid & 63;
    const int m16  = lane & 15;
    const int g4   = lane >> 4;
    const int wm   = w >> 1, wn = w & 1;

    const int row0 = blockIdx.y * 128;
    const int col0 = blockIdx.x * 128;

    const short* Ab = A  + (size_t)row0 * K;
    const short* Bb = Bt + (size_t)col0 * K;

    const int trow = tid >> 3;
    const int soct = (tid & 7) ^ (trow & 7);

    f32x4 acc[4][4];
#pragma unroll
    for (int i = 0; i < 4; ++i)
#pragma unroll
        for (int j = 0; j < 4; ++j) acc[i][j] = (f32x4){0.f, 0.f, 0.f, 0.f};

    for (int k0 = 0; k0 < K; k0 += 64) {
#pragma unroll
        for (int r = 0; r < 4; ++r) {
            const short* gp = Ab + (size_t)(r * 32 + trow) * K + k0 + soct * 8;
            short* lp = &As[(size_t)(r * 256 + w * 64) * 8];
            __builtin_amdgcn_global_load_lds(
                (const __attribute__((address_space(1))) void*)gp,
                (__attribute__((address_space(3))) void*)lp, 16, 0, 0);
        }
#pragma unroll
        for (int r = 0; r < 4; ++r) {
            const short* gp = Bb + (size_t)(r * 32 + trow) * K + k0 + soct * 8;
            short* lp = &Bs[(size_t)(r * 256 + w * 64) * 8];
            __builtin_amdgcn_global_load_lds(
                (const __attribute__((address_space(1))) void*)gp,
                (__attribute__((address_space(3))) void*)lp, 16, 0, 0);
        }
        __syncthreads();

#pragma unroll
        for (int kc = 0; kc < 2; ++kc) {
            bf16x8 a[4], b[4];
            const int swz = (kc * 4 + g4) ^ (m16 & 7);
#pragma unroll
            for (int s = 0; s < 4; ++s) {
                const int rowA = wm * 64 + s * 16 + m16;
                a[s] = *(const bf16x8*)&As[rowA * 64 + swz * 8];
                const int rowB = wn * 64 + s * 16 + m16;
                b[s] = *(const bf16x8*)&Bs[rowB * 64 + swz * 8];
            }
#pragma unroll
            for (int i = 0; i < 4; ++i)
#pragma unroll
                for (int j = 0; j < 4; ++j)
                    acc[i][j] = __builtin_amdgcn_mfma_f32_16x16x32_bf16(
                        a[i], b[j], acc[i][j], 0, 0, 0);
        }
        __syncthreads();
    }

#pragma unroll
    for (int i = 0; i < 4; ++i) {
        const int mbase = row0 + wm * 64 + i * 16 + g4 * 4;
#pragma unroll
        for (int j = 0; j < 4; ++j) {
            const int n = col0 + wn * 64 + j * 16 + m16;
#pragma unroll
            for (int r = 0; r < 4; ++r)
                C[(size_t)(mbase + r) * N + n] = acc[i][j][r];
        }
    }
}

// ------------- RoPE from C3 (B,S,3072) fp32 -> bf16 split layout -------------
__global__ __launch_bounds__(256) void rope_conv_kernel(
    const float* __restrict__ C3, short* __restrict__ Y,
    const int* __restrict__ pos_ids, int NHx, int colOff, float scale, int total)
{
    int idx = blockIdx.x * blockDim.x + threadIdx.x;
    if (idx >= total) return;
    const int i = idx & 63;
    int rest = idx >> 6;
    const int s = rest % Sq; rest /= Sq;
    const int h = rest % NHx;
    const int b = rest / NHx;

    const int pos = pos_ids[b * Sq + s];
    const float e   = -(float)(2 * i) * (1.0f / (float)HDn);
    const float inv = powf(500000.0f, e);
    const float f   = (float)pos * inv;
    const float c   = cosf(f);
    const float sn  = sinf(f);

    const float* src = C3 + ((size_t)(b * Sq + s)) * 3072 + colOff + h * HDn;
    const float x1 = src[i];
    const float x2 = src[i + 64];
    const size_t dst = (((size_t)b * NHx + h) * Sq + s) * HDn;
    Y[dst + i]      = f2b((x1 * c - x2 * sn) * scale);
    Y[dst + i + 64] = f2b((x2 * c + x1 * sn) * scale);
}

// ------------- V region of C3 -> bf16 transposed (B,KV,HD,S) -------------
__global__ __launch_bounds__(256) void vconv_kernel(
    const float* __restrict__ C3, short* __restrict__ Vt)
{
    __shared__ float t[32][33];
    const int bk = blockIdx.z;
    const int b  = bk >> 2, kv = bk & 3;
    const int s0 = blockIdx.x * 32;
    const int d0 = blockIdx.y * 32;
    const int tx = threadIdx.x, ty = threadIdx.y;

#pragma unroll
    for (int r = 0; r < 4; ++r) {
        const int row = ty + 8 * r;
        t[row][tx] = C3[((size_t)(b * Sq + s0 + row)) * 3072 + 2560 + kv * HDn + d0 + tx];
    }
    __syncthreads();
#pragma unroll
    for (int r = 0; r < 4; ++r) {
        const int row = ty + 8 * r;
        Vt[((size_t)bk * HDn + d0 + row) * Sq + s0 + tx] = f2b(t[tx][row]);
    }
}

// ------------- Block-cooperative MFMA flash attention, KQ orientation -------------
// 256 threads = 4 waves; block covers 128 queries (each wave: two 16-q tiles,
// at q0+w*16 and q0+64+w*16). 64-key chunks staged in LDS, shared by all waves
// and both q-tiles (each K/V LDS read feeds 2 MFMAs).
// K is staged with PERMUTED rows: phys key at LDS row pi so that the exp'd
// score regs form a 16x16x32 B-fragment directly (PV needs no LDS round-trip
// and uses b128 V reads). pi: row r=f*16+g4*4+i <-> phys key
// (f>>1)*32 + g4*8 + (f&1)*4 + i.
// Qb: (B,H,S,HD) bf16 pre-scaled by log2(e)/sqrt(HD). Kb: (B,KV,S,HD) bf16.
// Vtb: (B,KV,HD,S) bf16. AOb: (B,S,H*HD) bf16.
__global__ __launch_bounds__(256, 2) void fattn_kernel(
    const short* __restrict__ Qb, const short* __restrict__ Kb,
    const short* __restrict__ Vtb, short* __restrict__ AOb)
{
    __shared__ __align__(16) short Ks[64 * 128];   // [perm key][dim], oct-swizzled
    __shared__ __align__(16) short Vs[128 * 64];   // [dim][key], oct-swizzled

    const int tid  = threadIdx.x;
    const int w    = tid >> 6;
    const int lane = tid & 63;
    const int m16  = lane & 15;
    const int g4   = lane >> 4;

    // balanced mapping: blocks i and i+256 have complementary q-tiles
    const int i    = blockIdx.x;
    const int half = i >> 8;
    const int k4   = i & 15;
    const int qt   = half ? k4 : 15 - k4;   // 0..15, heavy (15) first in dispatch
    const int bh   = i >> 4;                // 0..31
    const int h    = bh & 15;
    const int b    = bh >> 4;
    const int kv   = h >> 2;
    const int q0   = qt << 7;               // 128 queries per block
    const int qA   = q0 + w * 16;            // tile0 queries
    const int qB   = q0 + 64 + w * 16;       // tile1 queries

    // Q B-frags for both tiles: B[k=dim g4*8+j][n=query m16]
    bf16x8 qf[2][4];
#pragma unroll
    for (int j = 0; j < 2; ++j) {
        const short* qp = Qb + (((size_t)b * Hn + h) * Sq + (j ? qB : qA) + m16) * HDn + g4 * 8;
#pragma unroll
        for (int c = 0; c < 4; ++c) qf[j][c] = *(const bf16x8*)(qp + c * 32);
    }

    const short* kbase = Kb  + ((size_t)b * KVn + kv) * Sq * HDn;
    const short* vbase = Vtb + ((size_t)b * KVn + kv) * (size_t)HDn * Sq;

    // staging source pointers (loop-invariant part)
    const short* gpK[4];
    const short* gpV[4];
#pragma unroll
    for (int r = 0; r < 4; ++r) {
        const int ci = r * 256 + tid;
        const int R  = ci >> 4, o = ci & 15;          // LDS K row, oct
        const int hf = (R >> 5) & 1, Rl = R & 31;
        const int phys = hf * 32 + ((Rl >> 2) & 3) * 8 + ((Rl >> 4) & 1) * 4 + (Rl & 3);
        gpK[r] = kbase + (size_t)phys * HDn + (o ^ (R & 7)) * 8;
        const int d = ci >> 3, ov = ci & 7;           // V dim row, oct
        gpV[r] = vbase + (size_t)d * Sq + (ov ^ (d & 7)) * 8;
    }

    f32x4 Ot[2][8];
#pragma unroll
    for (int j = 0; j < 2; ++j)
#pragma unroll
        for (int t = 0; t < 8; ++t) Ot[j][t] = (f32x4){0.f, 0.f, 0.f, 0.f};
    float mcur[2] = {-1e30f, -1e30f}, lcur[2] = {0.f, 0.f};

    const int nch = qt * 2 + 2;
    for (int ch = 0; ch < nch; ++ch) {
        const int kt = ch << 6;

#pragma unroll
        for (int r = 0; r < 4; ++r) {
            const short* gp = gpK[r] + (size_t)kt * HDn;
            short* lp = &Ks[(size_t)(r * 256 + w * 64) * 8];
            __builtin_amdgcn_global_load_lds(
                (const __attribute__((address_space(1))) void*)gp,
                (__attribute__((address_space(3))) void*)lp, 16, 0, 0);
        }
#pragma unroll
        for (int r = 0; r < 4; ++r) {
            const short* gp = gpV[r] + kt;
            short* lp = &Vs[(size_t)(r * 256 + w * 64) * 8];
            __builtin_amdgcn_global_load_lds(
                (const __attribute__((address_space(1))) void*)gp,
                (__attribute__((address_space(3))) void*)lp, 16, 0, 0);
        }
        __syncthreads();

        const bool last  = (ch == nch - 1);
        const bool diag0 = (ch == nch - 2);

        // ---- scores for both tiles, sharing every K-frag read ----
        f32x4 sc0[4], sc1[4];
#pragma unroll
        for (int f = 0; f < 4; ++f) {
            f32x4 a0 = (f32x4){0.f, 0.f, 0.f, 0.f};
            f32x4 a1 = (f32x4){0.f, 0.f, 0.f, 0.f};
            const int krow = f * 16 + m16;
#pragma unroll
            for (int c = 0; c < 4; ++c) {
                bf16x8 kf = *(const bf16x8*)&Ks[krow * 128 + (((c * 4 + g4) ^ (m16 & 7)) * 8)];
                a0 = __builtin_amdgcn_mfma_f32_16x16x32_bf16(kf, qf[0][c], a0, 0, 0, 0);
                a1 = __builtin_amdgcn_mfma_f32_16x16x32_bf16(kf, qf[1][c], a1, 0, 0, 0);
            }
            sc0[f] = a0; sc1[f] = a1;
        }

        // ---- causal masks (phys key = kt + (f>>1)*32 + g4*8 + (f&1)*4 + i) ----
        if (diag0) {
            const int qg = qA + m16;
#pragma unroll
            for (int f = 0; f < 4; ++f)
#pragma unroll
                for (int ii = 0; ii < 4; ++ii) {
                    const int kg = kt + (f >> 1) * 32 + g4 * 8 + (f & 1) * 4 + ii;
                    if (kg > qg) sc0[f][ii] = -1e30f;
                }
        }
        if (last) {
            const int qg = qB + m16;
#pragma unroll
            for (int f = 0; f < 4; ++f)
#pragma unroll
                for (int ii = 0; ii < 4; ++ii) {
                    const int kg = kt + (f >> 1) * 32 + g4 * 8 + (f & 1) * 4 + ii;
                    if (kg > qg) sc1[f][ii] = -1e30f;
                }
        }

        // ---- online softmax per tile (in-lane over 16 regs + 2 shuffles) ----
        bf16x8 pf0[2], pf1[2];
        if (!last) {
            float mx = sc0[0][0];
#pragma unroll
            for (int f = 0; f < 4; ++f)
#pragma unroll
                for (int ii = 0; ii < 4; ++ii) mx = fmaxf(mx, sc0[f][ii]);
            mx = fmaxf(mx, __shfl_xor(mx, 16));
            mx = fmaxf(mx, __shfl_xor(mx, 32));
            const float nm = fmaxf(mcur[0], mx);
            const float alpha = exp2f(mcur[0] - nm);
            mcur[0] = nm;
            float ps = 0.f;
#pragma unroll
            for (int f = 0; f < 4; ++f)
#pragma unroll
                for (int ii = 0; ii < 4; ++ii) {
                    sc0[f][ii] = exp2f(sc0[f][ii] - nm);
                    ps += sc0[f][ii];
                }
            ps += __shfl_xor(ps, 16);
            ps += __shfl_xor(ps, 32);
            lcur[0] = lcur[0] * alpha + ps;
#pragma unroll
            for (int t = 0; t < 8; ++t)
#pragma unroll
                for (int ii = 0; ii < 4; ++ii) Ot[0][t][ii] *= alpha;
#pragma unroll
            for (int hf = 0; hf < 2; ++hf) {
                bf16x8 p;
#pragma unroll
                for (int j8 = 0; j8 < 8; ++j8)
                    p[j8] = f2b(j8 < 4 ? sc0[hf * 2][j8] : sc0[hf * 2 + 1][j8 - 4]);
                pf0[hf] = p;
            }
        }
        {
            float mx = sc1[0][0];
#pragma unroll
            for (int f = 0; f < 4; ++f)
#pragma unroll
                for (int ii = 0; ii < 4; ++ii) mx = fmaxf(mx, sc1[f][ii]);
            mx = fmaxf(mx, __shfl_xor(mx, 16));
            mx = fmaxf(mx, __shfl_xor(mx, 32));
            const float nm = fmaxf(mcur[1], mx);
            const float alpha = exp2f(mcur[1] - nm);
            mcur[1] = nm;
            float ps = 0.f;
#pragma unroll
            for (int f = 0; f < 4; ++f)
#pragma unroll
                for (int ii = 0; ii < 4; ++ii) {
                    sc1[f][ii] = exp2f(sc1[f][ii] - nm);
                    ps += sc1[f][ii];
                }
            ps += __shfl_xor(ps, 16);
            ps += __shfl_xor(ps, 32);
            lcur[1] = lcur[1] * alpha + ps;
#pragma unroll
            for (int t = 0; t < 8; ++t)
#pragma unroll
                for (int ii = 0; ii < 4; ++ii) Ot[1][t][ii] *= alpha;
#pragma unroll
            for (int hf = 0; hf < 2; ++hf) {
                bf16x8 p;
#pragma unroll
                for (int j8 = 0; j8 < 8; ++j8)
                    p[j8] = f2b(j8 < 4 ? sc1[hf * 2][j8] : sc1[hf * 2 + 1][j8 - 4]);
                pf1[hf] = p;
            }
        }

        // ---- PV: O^T[d][q] += V^T[d][k] * P[k][q], sharing every V-frag read ----
#pragma unroll
        for (int t = 0; t < 8; ++t) {
            const int d = t * 16 + m16;
            bf16x8 vfa = *(const bf16x8*)&Vs[d * 64 + ((g4 ^ (d & 7)) * 8)];
            bf16x8 vfb = *(const bf16x8*)&Vs[d * 64 + (((4 + g4) ^ (d & 7)) * 8)];
            if (!last) {
                Ot[0][t] = __builtin_amdgcn_mfma_f32_16x16x32_bf16(vfa, pf0[0], Ot[0][t], 0, 0, 0);
                Ot[0][t] = __builtin_amdgcn_mfma_f32_16x16x32_bf16(vfb, pf0[1], Ot[0][t], 0, 0, 0);
            }
            Ot[1][t] = __builtin_amdgcn_mfma_f32_16x16x32_bf16(vfa, pf1[0], Ot[1][t], 0, 0, 0);
            Ot[1][t] = __builtin_amdgcn_mfma_f32_16x16x32_bf16(vfb, pf1[1], Ot[1][t], 0, 0, 0);
        }
        __syncthreads();
    }

    // ---- epilogue ----
#pragma unroll
    for (int j = 0; j < 2; ++j) {
        const float inv = 1.0f / lcur[j];
        short* op = AOb + ((size_t)b * Sq + (j ? qB : qA) + m16) * (Hn * HDn) + h * HDn + g4 * 4;
#pragma unroll
        for (int t = 0; t < 8; ++t) {
            short4 o;
            o.x = f2b(Ot[j][t][0] * inv);
            o.y = f2b(Ot[j][t][1] * inv);
            o.z = f2b(Ot[j][t][2] * inv);
            o.w = f2b(Ot[j][t][3] * inv);
            *(short4*)(op + t * 16) = o;
        }
    }
}

extern "C" void kernel_launch(void* const* d_in, const int* in_sizes, int n_in,
                              void* d_out, int out_size, void* d_ws, size_t ws_size,
                              hipStream_t stream)
{
    const float* x   = (const float*)d_in[0];
    const float* wq  = (const float*)d_in[1];
    const float* wk  = (const float*)d_in[2];
    const float* wv  = (const float*)d_in[3];
    const float* wo  = (const float*)d_in[4];
    const int* pos   = (const int*)d_in[6];
    float* out = (float*)d_out;

    const int M = Bsz * Sq;            // 4096
    const size_t nX  = (size_t)M * Dm; // 8388608

    short* xb    = (short*)d_ws;
    short* wqkvT = xb + nX;                       // 3072 x 2048
    short* woT   = wqkvT + (size_t)3072 * Dm;     // 2048 x 2048
    float* C3    = (float*)(woT + (size_t)Dm * Dm);
    short* Qb    = (short*)(C3 + (size_t)M * 3072);
    short* Kb    = Qb + nX;
    short* Vtb   = Kb + (size_t)Bsz * KVn * Sq * HDn;
    short* AOb   = Vtb + (size_t)Bsz * KVn * Sq * HDn;

    // --- conversions ---
    f2b_kernel<<<(nX / 4 + 255) / 256, 256, 0, stream>>>(x, xb, nX / 4);
    {
        dim3 blk(32, 8);
        wconvT_kernel<<<dim3(2048 / 32, Dm / 32), blk, 0, stream>>>(wq, wqkvT, 2048, 0);
        wconvT_kernel<<<dim3(512 / 32,  Dm / 32), blk, 0, stream>>>(wk, wqkvT, 512,  2048);
        wconvT_kernel<<<dim3(512 / 32,  Dm / 32), blk, 0, stream>>>(wv, wqkvT, 512,  2560);
        wconvT_kernel<<<dim3(2048 / 32, Dm / 32), blk, 0, stream>>>(wo, woT,   2048, 0);
    }

    // --- fused QKV projection: C3 (M x 3072) ---
    gemm_bt_kernel<<<dim3(3072 / 128, M / 128), 256, 0, stream>>>(
        xb, wqkvT, C3, M, 3072, Dm);

    // --- RoPE + split/convert ---
    {
        // 1/sqrt(128) * log2(e): base-2 softmax
        const float qscale = 0.08838834764831845f * 1.4426950408889634f;
        int totQ = Bsz * Hn * Sq * 64;
        rope_conv_kernel<<<(totQ + 255) / 256, 256, 0, stream>>>(
            C3, Qb, pos, Hn, 0, qscale, totQ);
        int totK = Bsz * KVn * Sq * 64;
        rope_conv_kernel<<<(totK + 255) / 256, 256, 0, stream>>>(
            C3, Kb, pos, KVn, 2048, 1.0f, totK);
    }
    vconv_kernel<<<dim3(Sq / 32, HDn / 32, Bsz * KVn), dim3(32, 8), 0, stream>>>(
        C3, Vtb);

    // --- attention: one block per 128 q-rows, balanced order ---
    fattn_kernel<<<Bsz * Hn * (Sq / 128), 256, 0, stream>>>(Qb, Kb, Vtb, AOb);

    // --- output projection ---
    gemm_bt_kernel<<<dim3(Dm / 128, M / 128), 256, 0, stream>>>(
        AOb, woT, out, M, Dm, Dm);
}

// Round 7
// 348.719 us; speedup vs baseline: 17.3636x; 1.0804x over previous
//
#include <hip/hip_runtime.h>
#include <hip/hip_bf16.h>
#include <math.h>

#define Bsz 2
#define Sq  2048
#define Dm  2048
#define Hn  16
#define KVn 4
#define HDn 128

typedef __attribute__((ext_vector_type(8))) short bf16x8;
typedef __attribute__((ext_vector_type(4))) float f32x4;

__device__ __forceinline__ short f2b(float f) {
    __hip_bfloat16 h = __float2bfloat16(f);
    return *reinterpret_cast<short*>(&h);
}
__device__ __forceinline__ float b2f(short s) {
    __hip_bfloat16 h = *reinterpret_cast<__hip_bfloat16*>(&s);
    return __bfloat162float(h);
}

// ---------------- fp32 -> bf16 elementwise (x) ----------------
__global__ __launch_bounds__(256) void f2b_kernel(
    const float* __restrict__ X, short* __restrict__ Y, int n4)
{
    int i = blockIdx.x * 256 + threadIdx.x;
    if (i >= n4) return;
    float4 v = ((const float4*)X)[i];
    short4 o;
    o.x = f2b(v.x); o.y = f2b(v.y); o.z = f2b(v.z); o.w = f2b(v.w);
    ((short4*)Y)[i] = o;
}

// ------------- ALL weights -> transposed bf16 in one launch -------------
// Output rows 0..3071 -> wqkvT (wq|wk|wv), rows 3072..5119 -> woT.
__global__ __launch_bounds__(256) void wconv_all_kernel(
    const float* __restrict__ wq, const float* __restrict__ wk,
    const float* __restrict__ wv, const float* __restrict__ wo,
    short* __restrict__ wqkvT, short* __restrict__ woT)
{
    __shared__ float t[32][33];
    const int n0 = blockIdx.x * 32;   // global output row
    const int k0 = blockIdx.y * 32;
    const int tx = threadIdx.x, ty = threadIdx.y;

    const float* W; int Nsec, nloc; short* dst;
    if (n0 < 2048)      { W = wq; Nsec = 2048; nloc = n0;        dst = wqkvT + (size_t)n0 * Dm; }
    else if (n0 < 2560) { W = wk; Nsec = 512;  nloc = n0 - 2048; dst = wqkvT + (size_t)n0 * Dm; }
    else if (n0 < 3072) { W = wv; Nsec = 512;  nloc = n0 - 2560; dst = wqkvT + (size_t)n0 * Dm; }
    else                { W = wo; Nsec = 2048; nloc = n0 - 3072; dst = woT + (size_t)(n0 - 3072) * Dm; }

#pragma unroll
    for (int r = 0; r < 4; ++r) {
        const int row = ty + 8 * r;
        t[row][tx] = W[(size_t)(k0 + row) * Nsec + nloc + tx];
    }
    __syncthreads();
#pragma unroll
    for (int r = 0; r < 4; ++r) {
        const int row = ty + 8 * r;
        dst[(size_t)row * Dm + k0 + tx] = f2b(t[tx][row]);
    }
}

// ---------------- bf16 MFMA GEMM: C(MxN) = A(MxK) * Bt(NxK)^T ----------------
// OT = short (bf16 out) or float.
template <typename OT>
__global__ __launch_bounds__(256) void gemm_bt_kernel(
    const short* __restrict__ A, const short* __restrict__ Bt,
    OT* __restrict__ C, int M, int N, int K)
{
    __shared__ __align__(16) short As[128 * 64];
    __shared__ __align__(16) short Bs[128 * 64];

    const int tid  = threadIdx.x;
    const int w    = tid >> 6;
    const int lane = tid & 63;
    const int m16  = lane & 15;
    const int g4   = lane >> 4;
    const int wm   = w >> 1, wn = w & 1;

    const int row0 = blockIdx.y * 128;
    const int col0 = blockIdx.x * 128;

    const short* Ab = A  + (size_t)row0 * K;
    const short* Bb = Bt + (size_t)col0 * K;

    const int trow = tid >> 3;
    const int soct = (tid & 7) ^ (trow & 7);

    f32x4 acc[4][4];
#pragma unroll
    for (int i = 0; i < 4; ++i)
#pragma unroll
        for (int j = 0; j < 4; ++j) acc[i][j] = (f32x4){0.f, 0.f, 0.f, 0.f};

    for (int k0 = 0; k0 < K; k0 += 64) {
#pragma unroll
        for (int r = 0; r < 4; ++r) {
            const short* gp = Ab + (size_t)(r * 32 + trow) * K + k0 + soct * 8;
            short* lp = &As[(size_t)(r * 256 + w * 64) * 8];
            __builtin_amdgcn_global_load_lds(
                (const __attribute__((address_space(1))) void*)gp,
                (__attribute__((address_space(3))) void*)lp, 16, 0, 0);
        }
#pragma unroll
        for (int r = 0; r < 4; ++r) {
            const short* gp = Bb + (size_t)(r * 32 + trow) * K + k0 + soct * 8;
            short* lp = &Bs[(size_t)(r * 256 + w * 64) * 8];
            __builtin_amdgcn_global_load_lds(
                (const __attribute__((address_space(1))) void*)gp,
                (__attribute__((address_space(3))) void*)lp, 16, 0, 0);
        }
        __syncthreads();

#pragma unroll
        for (int kc = 0; kc < 2; ++kc) {
            bf16x8 a[4], b[4];
            const int swz = (kc * 4 + g4) ^ (m16 & 7);
#pragma unroll
            for (int s = 0; s < 4; ++s) {
                const int rowA = wm * 64 + s * 16 + m16;
                a[s] = *(const bf16x8*)&As[rowA * 64 + swz * 8];
                const int rowB = wn * 64 + s * 16 + m16;
                b[s] = *(const bf16x8*)&Bs[rowB * 64 + swz * 8];
            }
#pragma unroll
            for (int i = 0; i < 4; ++i)
#pragma unroll
                for (int j = 0; j < 4; ++j)
                    acc[i][j] = __builtin_amdgcn_mfma_f32_16x16x32_bf16(
                        a[i], b[j], acc[i][j], 0, 0, 0);
        }
        __syncthreads();
    }

#pragma unroll
    for (int i = 0; i < 4; ++i) {
        const int mbase = row0 + wm * 64 + i * 16 + g4 * 4;
#pragma unroll
        for (int j = 0; j < 4; ++j) {
            const int n = col0 + wn * 64 + j * 16 + m16;
#pragma unroll
            for (int r = 0; r < 4; ++r) {
                if constexpr (sizeof(OT) == 2)
                    C[(size_t)(mbase + r) * N + n] = f2b(acc[i][j][r]);
                else
                    C[(size_t)(mbase + r) * N + n] = acc[i][j][r];
            }
        }
    }
}

// ------------- RoPE (Q and K in one launch) from bf16 C3 -> bf16 split layout -------------
// hh (wave-uniform) 0..15 -> Q head, 16..19 -> K head.
__global__ __launch_bounds__(256) void rope_all_kernel(
    const short* __restrict__ C3b, short* __restrict__ Qb, short* __restrict__ Kb,
    const int* __restrict__ pos_ids, float qscale, int total)
{
    int idx = blockIdx.x * blockDim.x + threadIdx.x;
    if (idx >= total) return;
    const int i = idx & 63;
    int rest = idx >> 6;
    const int s  = rest % Sq; rest /= Sq;
    const int hh = rest % 20;
    const int b  = rest / 20;

    const bool isQ = hh < 16;
    const int h      = isQ ? hh : hh - 16;
    const int colOff = isQ ? 0 : 2048;
    const int NHx    = isQ ? Hn : KVn;
    const float scale = isQ ? qscale : 1.0f;
    short* Y = isQ ? Qb : Kb;

    const int pos = pos_ids[b * Sq + s];
    const float e   = -(float)(2 * i) * (1.0f / (float)HDn);
    const float inv = powf(500000.0f, e);
    const float f   = (float)pos * inv;
    const float c   = cosf(f);
    const float sn  = sinf(f);

    const short* src = C3b + ((size_t)(b * Sq + s)) * 3072 + colOff + h * HDn;
    const float x1 = b2f(src[i]);
    const float x2 = b2f(src[i + 64]);
    const size_t dst = (((size_t)b * NHx + h) * Sq + s) * HDn;
    Y[dst + i]      = f2b((x1 * c - x2 * sn) * scale);
    Y[dst + i + 64] = f2b((x2 * c + x1 * sn) * scale);
}

// ------------- V region of bf16 C3 -> transposed (B,KV,HD,S) bf16 -------------
__global__ __launch_bounds__(256) void vconv_kernel(
    const short* __restrict__ C3b, short* __restrict__ Vt)
{
    __shared__ short t[32][34];
    const int bk = blockIdx.z;
    const int b  = bk >> 2, kv = bk & 3;
    const int s0 = blockIdx.x * 32;
    const int d0 = blockIdx.y * 32;
    const int tx = threadIdx.x, ty = threadIdx.y;

#pragma unroll
    for (int r = 0; r < 4; ++r) {
        const int row = ty + 8 * r;
        t[row][tx] = C3b[((size_t)(b * Sq + s0 + row)) * 3072 + 2560 + kv * HDn + d0 + tx];
    }
    __syncthreads();
#pragma unroll
    for (int r = 0; r < 4; ++r) {
        const int row = ty + 8 * r;
        Vt[((size_t)bk * HDn + d0 + row) * Sq + s0 + tx] = t[tx][row];
    }
}

// ------------- Block-cooperative MFMA flash attention, KQ orientation -------------
// 4 waves, 128 queries/block (two 16-q tiles per wave). Double-buffered 64-key
// chunks: prefetch for chunk ch+1 issued right after the barrier releasing its
// buffer, overlapping the staging latency with chunk ch's compute. One barrier
// per chunk.
__global__ __launch_bounds__(256, 2) void fattn_kernel(
    const short* __restrict__ Qb, const short* __restrict__ Kb,
    const short* __restrict__ Vtb, short* __restrict__ AOb)
{
    __shared__ __align__(16) short Ks[2][64 * 128];   // [buf][perm key][dim], oct-swizzled
    __shared__ __align__(16) short Vs[2][128 * 64];   // [buf][dim][key], oct-swizzled

    const int tid  = threadIdx.x;
    const int w    = tid >> 6;
    const int lane = tid & 63;
    const int m16  = lane & 15;
    const int g4   = lane >> 4;

    // balanced mapping: blocks i and i+256 have complementary q-tiles
    const int i    = blockIdx.x;
    const int half = i >> 8;
    const int k4   = i & 15;
    const int qt   = half ? k4 : 15 - k4;
    const int bh   = i >> 4;
    const int h    = bh & 15;
    const int b    = bh >> 4;
    const int kv   = h >> 2;
    const int q0   = qt << 7;
    const int qA   = q0 + w * 16;
    const int qB   = q0 + 64 + w * 16;

    bf16x8 qf[2][4];
#pragma unroll
    for (int j = 0; j < 2; ++j) {
        const short* qp = Qb + (((size_t)b * Hn + h) * Sq + (j ? qB : qA) + m16) * HDn + g4 * 8;
#pragma unroll
        for (int c = 0; c < 4; ++c) qf[j][c] = *(const bf16x8*)(qp + c * 32);
    }

    const short* kbase = Kb  + ((size_t)b * KVn + kv) * Sq * HDn;
    const short* vbase = Vtb + ((size_t)b * KVn + kv) * (size_t)HDn * Sq;

    // staging source pointers (loop-invariant part)
    const short* gpK[4];
    const short* gpV[4];
#pragma unroll
    for (int r = 0; r < 4; ++r) {
        const int ci = r * 256 + tid;
        const int R  = ci >> 4, o = ci & 15;          // LDS K row, oct
        const int hf = (R >> 5) & 1, Rl = R & 31;
        const int phys = hf * 32 + ((Rl >> 2) & 3) * 8 + ((Rl >> 4) & 1) * 4 + (Rl & 3);
        gpK[r] = kbase + (size_t)phys * HDn + (o ^ (R & 7)) * 8;
        const int d = ci >> 3, ov = ci & 7;           // V dim row, oct
        gpV[r] = vbase + (size_t)d * Sq + (ov ^ (d & 7)) * 8;
    }

    f32x4 Ot[2][8];
#pragma unroll
    for (int j = 0; j < 2; ++j)
#pragma unroll
        for (int t = 0; t < 8; ++t) Ot[j][t] = (f32x4){0.f, 0.f, 0.f, 0.f};
    float mcur[2] = {-1e30f, -1e30f}, lcur[2] = {0.f, 0.f};

    const int nch = qt * 2 + 2;

    auto stage = [&](int ch, int buf) {
        const size_t kt = (size_t)(ch << 6);
#pragma unroll
        for (int r = 0; r < 4; ++r) {
            const short* gp = gpK[r] + kt * HDn;
            short* lp = &Ks[buf][(size_t)(r * 256 + w * 64) * 8];
            __builtin_amdgcn_global_load_lds(
                (const __attribute__((address_space(1))) void*)gp,
                (__attribute__((address_space(3))) void*)lp, 16, 0, 0);
        }
#pragma unroll
        for (int r = 0; r < 4; ++r) {
            const short* gp = gpV[r] + kt;
            short* lp = &Vs[buf][(size_t)(r * 256 + w * 64) * 8];
            __builtin_amdgcn_global_load_lds(
                (const __attribute__((address_space(1))) void*)gp,
                (__attribute__((address_space(3))) void*)lp, 16, 0, 0);
        }
    };

    stage(0, 0);

    for (int ch = 0; ch < nch; ++ch) {
        const int cur = ch & 1;
        const int kt  = ch << 6;

        __syncthreads();   // loads for buf[cur] done; prior readers of buf[cur^1]... (see notes)
        if (ch + 1 < nch) stage(ch + 1, cur ^ 1);

        const bool last  = (ch == nch - 1);
        const bool diag0 = (ch == nch - 2);

        const short* KsC = Ks[cur];
        const short* VsC = Vs[cur];

        // ---- scores for both tiles, sharing every K-frag read ----
        f32x4 sc0[4], sc1[4];
#pragma unroll
        for (int f = 0; f < 4; ++f) {
            f32x4 a0 = (f32x4){0.f, 0.f, 0.f, 0.f};
            f32x4 a1 = (f32x4){0.f, 0.f, 0.f, 0.f};
            const int krow = f * 16 + m16;
#pragma unroll
            for (int c = 0; c < 4; ++c) {
                bf16x8 kf = *(const bf16x8*)&KsC[krow * 128 + (((c * 4 + g4) ^ (m16 & 7)) * 8)];
                a0 = __builtin_amdgcn_mfma_f32_16x16x32_bf16(kf, qf[0][c], a0, 0, 0, 0);
                a1 = __builtin_amdgcn_mfma_f32_16x16x32_bf16(kf, qf[1][c], a1, 0, 0, 0);
            }
            sc0[f] = a0; sc1[f] = a1;
        }

        // ---- causal masks (phys key = kt + (f>>1)*32 + g4*8 + (f&1)*4 + i) ----
        if (diag0) {
            const int qg = qA + m16;
#pragma unroll
            for (int f = 0; f < 4; ++f)
#pragma unroll
                for (int ii = 0; ii < 4; ++ii) {
                    const int kg = kt + (f >> 1) * 32 + g4 * 8 + (f & 1) * 4 + ii;
                    if (kg > qg) sc0[f][ii] = -1e30f;
                }
        }
        if (last) {
            const int qg = qB + m16;
#pragma unroll
            for (int f = 0; f < 4; ++f)
#pragma unroll
                for (int ii = 0; ii < 4; ++ii) {
                    const int kg = kt + (f >> 1) * 32 + g4 * 8 + (f & 1) * 4 + ii;
                    if (kg > qg) sc1[f][ii] = -1e30f;
                }
        }

        // ---- online softmax per tile ----
        bf16x8 pf0[2], pf1[2];
        if (!last) {
            float mx = sc0[0][0];
#pragma unroll
            for (int f = 0; f < 4; ++f)
#pragma unroll
                for (int ii = 0; ii < 4; ++ii) mx = fmaxf(mx, sc0[f][ii]);
            mx = fmaxf(mx, __shfl_xor(mx, 16));
            mx = fmaxf(mx, __shfl_xor(mx, 32));
            const float nm = fmaxf(mcur[0], mx);
            const float alpha = exp2f(mcur[0] - nm);
            mcur[0] = nm;
            float ps = 0.f;
#pragma unroll
            for (int f = 0; f < 4; ++f)
#pragma unroll
                for (int ii = 0; ii < 4; ++ii) {
                    sc0[f][ii] = exp2f(sc0[f][ii] - nm);
                    ps += sc0[f][ii];
                }
            ps += __shfl_xor(ps, 16);
            ps += __shfl_xor(ps, 32);
            lcur[0] = lcur[0] * alpha + ps;
#pragma unroll
            for (int t = 0; t < 8; ++t)
#pragma unroll
                for (int ii = 0; ii < 4; ++ii) Ot[0][t][ii] *= alpha;
#pragma unroll
            for (int hf = 0; hf < 2; ++hf) {
                bf16x8 p;
#pragma unroll
                for (int j8 = 0; j8 < 8; ++j8)
                    p[j8] = f2b(j8 < 4 ? sc0[hf * 2][j8] : sc0[hf * 2 + 1][j8 - 4]);
                pf0[hf] = p;
            }
        }
        {
            float mx = sc1[0][0];
#pragma unroll
            for (int f = 0; f < 4; ++f)
#pragma unroll
                for (int ii = 0; ii < 4; ++ii) mx = fmaxf(mx, sc1[f][ii]);
            mx = fmaxf(mx, __shfl_xor(mx, 16));
            mx = fmaxf(mx, __shfl_xor(mx, 32));
            const float nm = fmaxf(mcur[1], mx);
            const float alpha = exp2f(mcur[1] - nm);
            mcur[1] = nm;
            float ps = 0.f;
#pragma unroll
            for (int f = 0; f < 4; ++f)
#pragma unroll
                for (int ii = 0; ii < 4; ++ii) {
                    sc1[f][ii] = exp2f(sc1[f][ii] - nm);
                    ps += sc1[f][ii];
                }
            ps += __shfl_xor(ps, 16);
            ps += __shfl_xor(ps, 32);
            lcur[1] = lcur[1] * alpha + ps;
#pragma unroll
            for (int t = 0; t < 8; ++t)
#pragma unroll
                for (int ii = 0; ii < 4; ++ii) Ot[1][t][ii] *= alpha;
#pragma unroll
            for (int hf = 0; hf < 2; ++hf) {
                bf16x8 p;
#pragma unroll
                for (int j8 = 0; j8 < 8; ++j8)
                    p[j8] = f2b(j8 < 4 ? sc1[hf * 2][j8] : sc1[hf * 2 + 1][j8 - 4]);
                pf1[hf] = p;
            }
        }

        // ---- PV: O^T[d][q] += V^T[d][k] * P[k][q] ----
#pragma unroll
        for (int t = 0; t < 8; ++t) {
            const int d = t * 16 + m16;
            bf16x8 vfa = *(const bf16x8*)&VsC[d * 64 + ((g4 ^ (d & 7)) * 8)];
            bf16x8 vfb = *(const bf16x8*)&VsC[d * 64 + (((4 + g4) ^ (d & 7)) * 8)];
            if (!last) {
                Ot[0][t] = __builtin_amdgcn_mfma_f32_16x16x32_bf16(vfa, pf0[0], Ot[0][t], 0, 0, 0);
                Ot[0][t] = __builtin_amdgcn_mfma_f32_16x16x32_bf16(vfb, pf0[1], Ot[0][t], 0, 0, 0);
            }
            Ot[1][t] = __builtin_amdgcn_mfma_f32_16x16x32_bf16(vfa, pf1[0], Ot[1][t], 0, 0, 0);
            Ot[1][t] = __builtin_amdgcn_mfma_f32_16x16x32_bf16(vfb, pf1[1], Ot[1][t], 0, 0, 0);
        }
    }

    // ---- epilogue ----
#pragma unroll
    for (int j = 0; j < 2; ++j) {
        const float inv = 1.0f / lcur[j];
        short* op = AOb + ((size_t)b * Sq + (j ? qB : qA) + m16) * (Hn * HDn) + h * HDn + g4 * 4;
#pragma unroll
        for (int t = 0; t < 8; ++t) {
            short4 o;
            o.x = f2b(Ot[j][t][0] * inv);
            o.y = f2b(Ot[j][t][1] * inv);
            o.z = f2b(Ot[j][t][2] * inv);
            o.w = f2b(Ot[j][t][3] * inv);
            *(short4*)(op + t * 16) = o;
        }
    }
}

extern "C" void kernel_launch(void* const* d_in, const int* in_sizes, int n_in,
                              void* d_out, int out_size, void* d_ws, size_t ws_size,
                              hipStream_t stream)
{
    const float* x   = (const float*)d_in[0];
    const float* wq  = (const float*)d_in[1];
    const float* wk  = (const float*)d_in[2];
    const float* wv  = (const float*)d_in[3];
    const float* wo  = (const float*)d_in[4];
    const int* pos   = (const int*)d_in[6];
    float* out = (float*)d_out;

    const int M = Bsz * Sq;            // 4096
    const size_t nX  = (size_t)M * Dm; // 8388608

    short* xb    = (short*)d_ws;
    short* wqkvT = xb + nX;                       // 3072 x 2048
    short* woT   = wqkvT + (size_t)3072 * Dm;     // 2048 x 2048
    short* C3b   = woT + (size_t)Dm * Dm;         // 4096 x 3072 bf16
    short* Qb    = C3b + (size_t)M * 3072;
    short* Kb    = Qb + nX;
    short* Vtb   = Kb + (size_t)Bsz * KVn * Sq * HDn;
    short* AOb   = Vtb + (size_t)Bsz * KVn * Sq * HDn;

    // --- conversions (2 launches) ---
    f2b_kernel<<<(nX / 4 + 255) / 256, 256, 0, stream>>>(x, xb, nX / 4);
    wconv_all_kernel<<<dim3(5120 / 32, Dm / 32), dim3(32, 8), 0, stream>>>(
        wq, wk, wv, wo, wqkvT, woT);

    // --- fused QKV projection -> bf16 C3 ---
    gemm_bt_kernel<short><<<dim3(3072 / 128, M / 128), 256, 0, stream>>>(
        xb, wqkvT, C3b, M, 3072, Dm);

    // --- RoPE (Q+K) in one launch ---
    {
        const float qscale = 0.08838834764831845f * 1.4426950408889634f;
        int tot = Bsz * (Hn + KVn) * Sq * 64;
        rope_all_kernel<<<(tot + 255) / 256, 256, 0, stream>>>(
            C3b, Qb, Kb, pos, qscale, tot);
    }
    vconv_kernel<<<dim3(Sq / 32, HDn / 32, Bsz * KVn), dim3(32, 8), 0, stream>>>(
        C3b, Vtb);

    // --- attention: one block per 128 q-rows, balanced order, dbuf staging ---
    fattn_kernel<<<Bsz * Hn * (Sq / 128), 256, 0, stream>>>(Qb, Kb, Vtb, AOb);

    // --- output projection (fp32 out) ---
    gemm_bt_kernel<float><<<dim3(Dm / 128, M / 128), 256, 0, stream>>>(
        AOb, woT, out, M, Dm, Dm);
}